// Round 3
// baseline (384.548 us; speedup 1.0000x reference)
//
#include <hip/hip_runtime.h>
#include <hip/hip_bf16.h>

#define NHEAD 8
#define DK_ 64
#define DM_ 512
#define S_LEN 4096
#define NTOK 8192

typedef __bf16 bf16x8 __attribute__((ext_vector_type(8)));
typedef float f32x4 __attribute__((ext_vector_type(4)));
typedef float f32x16 __attribute__((ext_vector_type(16)));
typedef unsigned int uint4v __attribute__((ext_vector_type(4)));

__device__ __forceinline__ unsigned short f2bf(float f) {
    union { float f; unsigned u; } x; x.f = f;
    unsigned u = x.u;
    u += 0x7FFFu + ((u >> 16) & 1u);   // round-to-nearest-even (inputs finite)
    return (unsigned short)(u >> 16);
}

// packed f32x2 -> bf16x2 (gfx950 HW op when available; RNE either way)
#if __has_builtin(__builtin_amdgcn_cvt_pk_bf16_f32)
__device__ __forceinline__ unsigned int pkbf(float a, float b) {
    auto r = __builtin_amdgcn_cvt_pk_bf16_f32(a, b);
    unsigned int u; __builtin_memcpy(&u, &r, 4); return u;
}
#else
__device__ __forceinline__ unsigned int pkbf(float a, float b) {
    return (unsigned)f2bf(a) | ((unsigned)f2bf(b) << 16);
}
#endif

#if __has_builtin(__builtin_amdgcn_exp2f)
#define EXP2F(x) __builtin_amdgcn_exp2f(x)
#else
#define EXP2F(x) exp2f(x)
#endif

// lane-half <-> reg exchange: new_a = {a_lo, b_lo}, new_b = {a_hi, b_hi}
#if __has_builtin(__builtin_amdgcn_permlane32_swap)
__device__ __forceinline__ void pl32swap(unsigned int& a, unsigned int& b) {
    auto r = __builtin_amdgcn_permlane32_swap(a, b, false, false);
    a = r[0]; b = r[1];
}
#else
__device__ __forceinline__ void pl32swap(unsigned int& a, unsigned int& b) {
    int lane = threadIdx.x & 63;
    unsigned int ax = __shfl_xor((int)a, 32, 64);
    unsigned int bx = __shfl_xor((int)b, 32, 64);
    unsigned int na = (lane < 32) ? a : bx;
    unsigned int nb = (lane < 32) ? ax : b;
    a = na; b = nb;
}
#endif

// async global->LDS, 16B per lane; LDS dest = wave-uniform base + lane*16
#define GLOAD_LDS16(gptr, ldsbase) \
    __builtin_amdgcn_global_load_lds((const __attribute__((address_space(1))) unsigned int*)(gptr), \
                                     (__attribute__((address_space(3))) unsigned int*)(ldsbase), 16, 0, 0)

// ---------- xcvt: Xbf[z][tok][dm] = bf16(x_z) ----------
__global__ __launch_bounds__(256) void xcvt(const float* __restrict__ q, const float* __restrict__ k,
                                            const float* __restrict__ v, unsigned short* __restrict__ Xbf) {
    int z = blockIdx.y;
    const float* X = (z == 0) ? q : (z == 1) ? k : v;
    size_t off = (size_t)blockIdx.x * 1024 + threadIdx.x * 4;
    float4 val = *(const float4*)&X[off];
    uint2 o; o.x = pkbf(val.x, val.y); o.y = pkbf(val.z, val.w);
    *(uint2*)&Xbf[(size_t)z * NTOK * DM_ + off] = o;
}

// ---------- kernel 0: Wt[z][n][k] = bf16(W_z[k][n]) ----------
__global__ __launch_bounds__(256) void wtrans(const float* __restrict__ Wq, const float* __restrict__ Wk,
                                              const float* __restrict__ Wv, const float* __restrict__ Wo,
                                              unsigned short* __restrict__ Wt) {
    int z = blockIdx.z;
    const float* W = (z == 0) ? Wq : (z == 1) ? Wk : (z == 2) ? Wv : Wo;
    unsigned short* out = Wt + (size_t)z * DM_ * DM_;
    __shared__ float t[64][65];
    int bn = blockIdx.x * 64, bk = blockIdx.y * 64;
    int tid = threadIdx.x;
    int r0 = tid >> 4, c4 = (tid & 15) * 4;
#pragma unroll
    for (int i = 0; i < 4; i++) {
        int r = r0 + i * 16;
        float4 v = *(const float4*)&W[(size_t)(bk + r) * DM_ + bn + c4];
        t[r][c4] = v.x; t[r][c4 + 1] = v.y; t[r][c4 + 2] = v.z; t[r][c4 + 3] = v.w;
    }
    __syncthreads();
    int n0 = tid >> 4, k4 = (tid & 15) * 4;
#pragma unroll
    for (int i = 0; i < 4; i++) {
        int n = n0 + i * 16;
        ushort4 o;
        o.x = f2bf(t[k4 + 0][n]); o.y = f2bf(t[k4 + 1][n]);
        o.z = f2bf(t[k4 + 2][n]); o.w = f2bf(t[k4 + 3][n]);
        *(ushort4*)&out[(size_t)(bn + n) * DM_ + bk + k4] = o;
    }
}

// shared epilogue for projection GEMMs
__device__ __forceinline__ void proj_epilogue(int z, f32x4 (&acc)[4][4], const float* bias,
                                              unsigned short* out, float scale,
                                              int m0, int n0, int mb, int nb, int ln, int qd) {
    float bvv[4];
#pragma unroll
    for (int nt = 0; nt < 4; nt++) bvv[nt] = bias[n0 + nb + nt * 16 + ln];
#pragma unroll
    for (int mt = 0; mt < 4; mt++) {
        int mrow0 = m0 + mb + mt * 16 + qd * 4;
        int b = mrow0 >> 12, s = mrow0 & 4095;
#pragma unroll
        for (int nt = 0; nt < 4; nt++) {
            int ncol = n0 + nb + nt * 16 + ln;
            int h = ncol >> 6, d = ncol & 63;
            if (z == 2) {
                uint2 o;
                o.x = pkbf((acc[mt][nt][0] + bvv[nt]) * scale, (acc[mt][nt][1] + bvv[nt]) * scale);
                o.y = pkbf((acc[mt][nt][2] + bvv[nt]) * scale, (acc[mt][nt][3] + bvv[nt]) * scale);
                *(uint2*)&out[((size_t)(b * NHEAD + h) * DK_ + d) * S_LEN + s] = o;
            } else {
#pragma unroll
                for (int r = 0; r < 4; r++)
                    out[((size_t)(b * NHEAD + h) * S_LEN + (s + r)) * DK_ + d] =
                        f2bf((acc[mt][nt][r] + bvv[nt]) * scale);
            }
        }
    }
}

// ---------- fused QKV projection from pre-converted bf16 X ----------
__global__ __launch_bounds__(256, 3) void qkv_bf(const unsigned short* __restrict__ Xbf,
                                                 const unsigned short* __restrict__ Wt,
                                                 const float* __restrict__ bq, const float* __restrict__ bk,
                                                 const float* __restrict__ bv,
                                                 unsigned short* __restrict__ Qh, unsigned short* __restrict__ Kh,
                                                 unsigned short* __restrict__ VhT) {
    int z = blockIdx.z;
    const unsigned short* X = Xbf + (size_t)z * NTOK * DM_;
    const unsigned short* W = Wt + (size_t)z * DM_ * DM_;
    const float* bias = (z == 0) ? bq : (z == 1) ? bk : bv;
    unsigned short* out = (z == 0) ? Qh : (z == 1) ? Kh : VhT;
    float scale = (z == 0) ? 0.125f * 1.44269504f : 1.0f;

    __shared__ unsigned short As[128 * 40];
    __shared__ unsigned short Bs[128 * 40];
    int tid = threadIdx.x;
    int n0 = blockIdx.x * 128, m0 = blockIdx.y * 128;
    int w = tid >> 6, lane = tid & 63;
    int ln = lane & 15, qd = lane >> 4;
    int mb = (w >> 1) * 64, nb = (w & 1) * 64;

    f32x4 acc[4][4];
#pragma unroll
    for (int i = 0; i < 4; i++)
#pragma unroll
        for (int j = 0; j < 4; j++) { f32x4 zz = {0.f, 0.f, 0.f, 0.f}; acc[i][j] = zz; }

    for (int kk = 0; kk < DM_; kk += 32) {
        __syncthreads();
#pragma unroll
        for (int i = 0; i < 2; i++) {
            int idx = i * 256 + tid;
            int row = idx >> 2, k8 = (idx & 3) * 8;
            uint4 va = *(const uint4*)&X[(size_t)(m0 + row) * DM_ + kk + k8];
            *(uint4*)&As[row * 40 + k8] = va;
            uint4 vb = *(const uint4*)&W[(size_t)(n0 + row) * DM_ + kk + k8];
            *(uint4*)&Bs[row * 40 + k8] = vb;
        }
        __syncthreads();
        bf16x8 af[4], bf[4];
#pragma unroll
        for (int mt = 0; mt < 4; mt++) af[mt] = *(const bf16x8*)&As[(mb + mt * 16 + ln) * 40 + qd * 8];
#pragma unroll
        for (int nt = 0; nt < 4; nt++) bf[nt] = *(const bf16x8*)&Bs[(nb + nt * 16 + ln) * 40 + qd * 8];
#pragma unroll
        for (int mt = 0; mt < 4; mt++)
#pragma unroll
            for (int nt = 0; nt < 4; nt++)
                acc[mt][nt] = __builtin_amdgcn_mfma_f32_16x16x32_bf16(af[mt], bf[nt], acc[mt][nt], 0, 0, 0);
    }
    proj_epilogue(z, acc, bias, out, scale, m0, n0, mb, nb, ln, qd);
}

// ---------- fallback fused QKV projection from fp32 X (small ws) ----------
__global__ __launch_bounds__(256, 3) void qkv_proj(const float* __restrict__ xq, const float* __restrict__ xk,
                                                   const float* __restrict__ xv, const unsigned short* __restrict__ Wt,
                                                   const float* __restrict__ bq, const float* __restrict__ bk,
                                                   const float* __restrict__ bv,
                                                   unsigned short* __restrict__ Qh, unsigned short* __restrict__ Kh,
                                                   unsigned short* __restrict__ VhT) {
    int z = blockIdx.z;
    const float* X = (z == 0) ? xq : (z == 1) ? xk : xv;
    const unsigned short* W = Wt + (size_t)z * DM_ * DM_;
    const float* bias = (z == 0) ? bq : (z == 1) ? bk : bv;
    unsigned short* out = (z == 0) ? Qh : (z == 1) ? Kh : VhT;
    float scale = (z == 0) ? 0.125f * 1.44269504f : 1.0f;

    __shared__ unsigned short As[128 * 40];
    __shared__ unsigned short Bs[128 * 40];
    int tid = threadIdx.x;
    int n0 = blockIdx.x * 128, m0 = blockIdx.y * 128;
    int w = tid >> 6, lane = tid & 63;
    int ln = lane & 15, qd = lane >> 4;
    int mb = (w >> 1) * 64, nb = (w & 1) * 64;

    f32x4 acc[4][4];
#pragma unroll
    for (int i = 0; i < 4; i++)
#pragma unroll
        for (int j = 0; j < 4; j++) { f32x4 zz = {0.f, 0.f, 0.f, 0.f}; acc[i][j] = zz; }

    for (int kk = 0; kk < DM_; kk += 32) {
        __syncthreads();
#pragma unroll
        for (int i = 0; i < 4; i++) {
            int idx = i * 256 + tid;
            int row = idx >> 3, k4 = (idx & 7) * 4;
            float4 v = *(const float4*)&X[(size_t)(m0 + row) * DM_ + kk + k4];
            uint2 o; o.x = pkbf(v.x, v.y); o.y = pkbf(v.z, v.w);
            *(uint2*)&As[row * 40 + k4] = o;
        }
#pragma unroll
        for (int i = 0; i < 2; i++) {
            int idx = i * 256 + tid;
            int row = idx >> 2, k8 = (idx & 3) * 8;
            uint4 v = *(const uint4*)&W[(size_t)(n0 + row) * DM_ + kk + k8];
            *(uint4*)&Bs[row * 40 + k8] = v;
        }
        __syncthreads();
        bf16x8 af[4], bf[4];
#pragma unroll
        for (int mt = 0; mt < 4; mt++) af[mt] = *(const bf16x8*)&As[(mb + mt * 16 + ln) * 40 + qd * 8];
#pragma unroll
        for (int nt = 0; nt < 4; nt++) bf[nt] = *(const bf16x8*)&Bs[(nb + nt * 16 + ln) * 40 + qd * 8];
#pragma unroll
        for (int mt = 0; mt < 4; mt++)
#pragma unroll
            for (int nt = 0; nt < 4; nt++)
                acc[mt][nt] = __builtin_amdgcn_mfma_f32_16x16x32_bf16(af[mt], bf[nt], acc[mt][nt], 0, 0, 0);
    }
    proj_epilogue(z, acc, bias, out, scale, m0, n0, mb, nb, ln, qd);
}

// ---------- flash attention (legacy single-pass, small-ws fallback) ----------
__global__ __launch_bounds__(256, 2) void flash_attn(const unsigned short* __restrict__ Qh,
                                                     const unsigned short* __restrict__ Kh,
                                                     const unsigned short* __restrict__ VhT,
                                                     unsigned short* __restrict__ Ao) {
    __shared__ unsigned short Ks[2][64 * 64];     // 16 KB
    __shared__ unsigned short Vs[2][64 * 64];     // 16 KB
    int i = blockIdx.x;
    int bh = (i & 7) + 8 * ((i >> 3) & 1);
    int qb = i >> 4;
    int tid = threadIdx.x;
    int w = tid >> 6, lane = tid & 63;
    int ln = lane & 31, hf = lane >> 5;
    int swz = ln & 7;
    int q0 = qb * 128 + w * 32;
    const unsigned short* Qp = Qh + (size_t)bh * S_LEN * DK_;
    const unsigned short* Kp = Kh + (size_t)bh * S_LEN * DK_;
    const unsigned short* Vp = VhT + (size_t)bh * DK_ * S_LEN;

    int sr = lane >> 3;
    int sc = (lane & 7) ^ sr;
    const unsigned short* ksrc = Kp + (size_t)(w * 16 + sr) * DK_ + sc * 8;
    const unsigned short* vsrc = Vp + (size_t)(w * 16 + sr) * S_LEN + sc * 8;

    bf16x8 qf[4];
#pragma unroll
    for (int s = 0; s < 4; s++)
        qf[s] = *(const bf16x8*)&Qp[(size_t)(q0 + ln) * DK_ + s * 16 + hf * 8];

    f32x16 oacc[2];
    { f32x16 z = {0.f}; oacc[0] = z; oacc[1] = z; }
    float lsum = 0.f;

    GLOAD_LDS16(ksrc, &Ks[0][w * 1024]);
    GLOAD_LDS16(ksrc + (size_t)8 * DK_, &Ks[0][w * 1024 + 512]);
    GLOAD_LDS16(vsrc, &Vs[0][w * 1024]);
    GLOAD_LDS16(vsrc + (size_t)8 * S_LEN, &Vs[0][w * 1024 + 512]);

    int p = 0;
    for (int ks = 0; ks < S_LEN; ks += 64, p ^= 1) {
        __syncthreads();
        if (ks + 64 < S_LEN) {
            const unsigned short* kn = ksrc + (size_t)(ks + 64) * DK_;
            const unsigned short* vn = vsrc + (ks + 64);
            GLOAD_LDS16(kn, &Ks[p ^ 1][w * 1024]);
            GLOAD_LDS16(kn + (size_t)8 * DK_, &Ks[p ^ 1][w * 1024 + 512]);
            GLOAD_LDS16(vn, &Vs[p ^ 1][w * 1024]);
            GLOAD_LDS16(vn + (size_t)8 * S_LEN, &Vs[p ^ 1][w * 1024 + 512]);
        }
        const unsigned short* KsT = &Ks[p][0];
        const unsigned short* VsT = &Vs[p][0];

#pragma unroll
        for (int kb = 0; kb < 2; kb++) {
            f32x16 st = {0.f};
#pragma unroll
            for (int s = 0; s < 4; s++) {
                bf16x8 kf = *(const bf16x8*)&KsT[(kb * 32 + ln) * 64 + ((2 * s + hf) ^ swz) * 8];
                st = __builtin_amdgcn_mfma_f32_32x32x16_bf16(kf, qf[s], st, 0, 0, 0);
            }
            float e[16];
#pragma unroll
            for (int r = 0; r < 16; r++) e[r] = EXP2F(st[r]);
            lsum += ((e[0] + e[1]) + (e[2] + e[3])) + ((e[4] + e[5]) + (e[6] + e[7]))
                  + ((e[8] + e[9]) + (e[10] + e[11])) + ((e[12] + e[13]) + (e[14] + e[15]));
            unsigned int g[8];
#pragma unroll
            for (int gi = 0; gi < 8; gi++) g[gi] = pkbf(e[2 * gi], e[2 * gi + 1]);
            pl32swap(g[0], g[2]); pl32swap(g[1], g[3]);
            pl32swap(g[4], g[6]); pl32swap(g[5], g[7]);
            bf16x8 b0, b1;
            { uint4v t = {g[0], g[1], g[2], g[3]}; __builtin_memcpy(&b0, &t, 16); }
            { uint4v t = {g[4], g[5], g[6], g[7]}; __builtin_memcpy(&b1, &t, 16); }
#pragma unroll
            for (int dt = 0; dt < 2; dt++) {
                int s0 = kb * 2;
                bf16x8 vf0 = *(const bf16x8*)&VsT[(dt * 32 + ln) * 64 + ((2 * s0 + hf) ^ swz) * 8];
                bf16x8 vf1 = *(const bf16x8*)&VsT[(dt * 32 + ln) * 64 + ((2 * s0 + 2 + hf) ^ swz) * 8];
                oacc[dt] = __builtin_amdgcn_mfma_f32_32x32x16_bf16(vf0, b0, oacc[dt], 0, 0, 0);
                oacc[dt] = __builtin_amdgcn_mfma_f32_32x32x16_bf16(vf1, b1, oacc[dt], 0, 0, 0);
            }
        }
    }

    float ltot = lsum + __shfl_xor(lsum, 32, 64);
    float inv = 1.0f / ltot;

    int bb = bh >> 3, hh = bh & 7;
    int token = bb * S_LEN + q0 + ln;
#pragma unroll
    for (int dt = 0; dt < 2; dt++)
#pragma unroll
        for (int gi = 0; gi < 8; gi++) {
            int d = dt * 32 + 2 * (gi & 1) + 8 * (gi >> 1) + 4 * hf;
            unsigned int o = pkbf(oacc[dt][2 * gi] * inv, oacc[dt][2 * gi + 1] * inv);
            *(unsigned int*)&Ao[(size_t)token * DM_ + hh * DK_ + d] = o;
        }
}

// ---------- split-K flash attention (32 q/wave, NSP-way key split) ----------
// Round-1 winner shape (NSP=2): 4 waves/SIMD. Kept as mid-tier fallback.
__global__ __launch_bounds__(256, 4) void flash_attn_sp(const unsigned short* __restrict__ Qh,
                                                        const unsigned short* __restrict__ Kh,
                                                        const unsigned short* __restrict__ VhT,
                                                        float* __restrict__ Opart,
                                                        float* __restrict__ lpart) {
    __shared__ unsigned short Ks[2][64 * 64];
    __shared__ unsigned short Vs[2][64 * 64];
    int i = blockIdx.x;
    int bh = (i & 7) + 8 * ((i >> 3) & 1);
    int qb = (i >> 4) & 31;
    int sp = i >> 9;
    int ks0 = sp * (S_LEN / 2);
    int ks1 = ks0 + (S_LEN / 2);
    int tid = threadIdx.x;
    int w = tid >> 6, lane = tid & 63;
    int ln = lane & 31, hf = lane >> 5;
    int swz = ln & 7;
    int q0 = qb * 128 + w * 32;
    const unsigned short* Qp = Qh + (size_t)bh * S_LEN * DK_;
    const unsigned short* Kp = Kh + (size_t)bh * S_LEN * DK_;
    const unsigned short* Vp = VhT + (size_t)bh * DK_ * S_LEN;

    int sr = lane >> 3;
    int sc = (lane & 7) ^ sr;
    const unsigned short* ksrc = Kp + (size_t)(w * 16 + sr) * DK_ + sc * 8;
    const unsigned short* vsrc = Vp + (size_t)(w * 16 + sr) * S_LEN + sc * 8;

    bf16x8 qf[4];
#pragma unroll
    for (int s = 0; s < 4; s++)
        qf[s] = *(const bf16x8*)&Qp[(size_t)(q0 + ln) * DK_ + s * 16 + hf * 8];

    f32x16 oacc[2];
    { f32x16 z = {0.f}; oacc[0] = z; oacc[1] = z; }
    float lsum = 0.f;

    GLOAD_LDS16(ksrc + (size_t)ks0 * DK_, &Ks[0][w * 1024]);
    GLOAD_LDS16(ksrc + (size_t)(ks0 + 8) * DK_, &Ks[0][w * 1024 + 512]);
    GLOAD_LDS16(vsrc + ks0, &Vs[0][w * 1024]);
    GLOAD_LDS16(vsrc + ks0 + (size_t)8 * S_LEN, &Vs[0][w * 1024 + 512]);

    int p = 0;
    for (int ks = ks0; ks < ks1; ks += 64, p ^= 1) {
        __syncthreads();
        if (ks + 64 < ks1) {
            const unsigned short* kn = ksrc + (size_t)(ks + 64) * DK_;
            const unsigned short* vn = vsrc + (ks + 64);
            GLOAD_LDS16(kn, &Ks[p ^ 1][w * 1024]);
            GLOAD_LDS16(kn + (size_t)8 * DK_, &Ks[p ^ 1][w * 1024 + 512]);
            GLOAD_LDS16(vn, &Vs[p ^ 1][w * 1024]);
            GLOAD_LDS16(vn + (size_t)8 * S_LEN, &Vs[p ^ 1][w * 1024 + 512]);
        }
        const unsigned short* KsT = &Ks[p][0];
        const unsigned short* VsT = &Vs[p][0];

#pragma unroll
        for (int kb = 0; kb < 2; kb++) {
            f32x16 st = {0.f};
#pragma unroll
            for (int s = 0; s < 4; s++) {
                bf16x8 kf = *(const bf16x8*)&KsT[(kb * 32 + ln) * 64 + ((2 * s + hf) ^ swz) * 8];
                st = __builtin_amdgcn_mfma_f32_32x32x16_bf16(kf, qf[s], st, 0, 0, 0);
            }
            float e[16];
#pragma unroll
            for (int r = 0; r < 16; r++) e[r] = EXP2F(st[r]);
            lsum += ((e[0] + e[1]) + (e[2] + e[3])) + ((e[4] + e[5]) + (e[6] + e[7]))
                  + ((e[8] + e[9]) + (e[10] + e[11])) + ((e[12] + e[13]) + (e[14] + e[15]));
            unsigned int g[8];
#pragma unroll
            for (int gi = 0; gi < 8; gi++) g[gi] = pkbf(e[2 * gi], e[2 * gi + 1]);
            pl32swap(g[0], g[2]); pl32swap(g[1], g[3]);
            pl32swap(g[4], g[6]); pl32swap(g[5], g[7]);
            bf16x8 b0, b1;
            { uint4v t = {g[0], g[1], g[2], g[3]}; __builtin_memcpy(&b0, &t, 16); }
            { uint4v t = {g[4], g[5], g[6], g[7]}; __builtin_memcpy(&b1, &t, 16); }
#pragma unroll
            for (int dt = 0; dt < 2; dt++) {
                int s0 = kb * 2;
                bf16x8 vf0 = *(const bf16x8*)&VsT[(dt * 32 + ln) * 64 + ((2 * s0 + hf) ^ swz) * 8];
                bf16x8 vf1 = *(const bf16x8*)&VsT[(dt * 32 + ln) * 64 + ((2 * s0 + 2 + hf) ^ swz) * 8];
                oacc[dt] = __builtin_amdgcn_mfma_f32_32x32x16_bf16(vf0, b0, oacc[dt], 0, 0, 0);
                oacc[dt] = __builtin_amdgcn_mfma_f32_32x32x16_bf16(vf1, b1, oacc[dt], 0, 0, 0);
            }
        }
    }

    float ltot = lsum + __shfl_xor(lsum, 32, 64);
    if (hf == 0)
        lpart[(size_t)sp * (16 * S_LEN) + (size_t)bh * S_LEN + q0 + ln] = ltot;

    int bb = bh >> 3, hh = bh & 7;
    int token = bb * S_LEN + q0 + ln;
    float* op = Opart + (size_t)sp * NTOK * DM_;
#pragma unroll
    for (int dt = 0; dt < 2; dt++)
#pragma unroll
        for (int gi = 0; gi < 8; gi++) {
            int d = dt * 32 + 2 * (gi & 1) + 8 * (gi >> 1) + 4 * hf;
            float2 o; o.x = oacc[dt][2 * gi]; o.y = oacc[dt][2 * gi + 1];
            *(float2*)&op[(size_t)token * DM_ + hh * DK_ + d] = o;
        }
}

// ---------- split-K flash v4: 64 queries/wave AND 4-way split ----------
// Round-2 post-mortem: 64q/wave halved LDS reads+conflicts (verified) but
// halving occupancy to 2 waves/SIMD cost more than the LDS win. v4 keeps the
// 2x arithmetic intensity AND restores 4 waves/SIMD via a 4-way key split:
// grid 1024 = 4 blocks/CU (LDS 4x32KB=128KB, VGPR 104 < 128 cap).
// s_setprio(1) around MFMA clusters (T5; cross-block phase diversity exists).
__global__ __launch_bounds__(256, 4) void flash_attn_sp4(const unsigned short* __restrict__ Qh,
                                                         const unsigned short* __restrict__ Kh,
                                                         const unsigned short* __restrict__ VhT,
                                                         float* __restrict__ Opart,
                                                         float* __restrict__ lpart) {
    __shared__ unsigned short Ks[2][64 * 64];     // 16 KB
    __shared__ unsigned short Vs[2][64 * 64];     // 16 KB
    int i = blockIdx.x;
    int bh = i & 15;
    int qb = (i >> 4) & 15;
    int sp = i >> 8;                               // 0..3 key-split quarter
    int ks0 = sp * (S_LEN / 4);
    int ks1 = ks0 + (S_LEN / 4);
    int tid = threadIdx.x;
    int w = tid >> 6, lane = tid & 63;
    int ln = lane & 31, hf = lane >> 5;
    int swz = ln & 7;
    int q0 = qb * 256 + w * 64;                    // wave covers queries q0..q0+63
    const unsigned short* Qp = Qh + (size_t)bh * S_LEN * DK_;
    const unsigned short* Kp = Kh + (size_t)bh * S_LEN * DK_;
    const unsigned short* Vp = VhT + (size_t)bh * DK_ * S_LEN;

    // staging geometry: wave w stages rows w*16..w*16+15 of each tile (2 x 1KB)
    int sr = lane >> 3;                            // 0..7
    int sc = (lane & 7) ^ sr;                      // XOR swizzle chunk
    const unsigned short* ksrc = Kp + (size_t)(w * 16 + sr) * DK_ + sc * 8;
    const unsigned short* vsrc = Vp + (size_t)(w * 16 + sr) * S_LEN + sc * 8;

    // Q fragments for both q-tiles (B operand: n = query, k = hf*8+j)
    bf16x8 qfA[4], qfB[4];
#pragma unroll
    for (int s = 0; s < 4; s++) {
        qfA[s] = *(const bf16x8*)&Qp[(size_t)(q0 + ln) * DK_ + s * 16 + hf * 8];
        qfB[s] = *(const bf16x8*)&Qp[(size_t)(q0 + 32 + ln) * DK_ + s * 16 + hf * 8];
    }

    f32x16 oaccA[2], oaccB[2];   // O^T per q-tile: [dt] 32 d x 32 q
    { f32x16 z = {0.f}; oaccA[0] = z; oaccA[1] = z; oaccB[0] = z; oaccB[1] = z; }
    float lsumA = 0.f, lsumB = 0.f;

    // prologue: DMA first tile of this split into buffer 0
    GLOAD_LDS16(ksrc + (size_t)ks0 * DK_, &Ks[0][w * 1024]);
    GLOAD_LDS16(ksrc + (size_t)(ks0 + 8) * DK_, &Ks[0][w * 1024 + 512]);
    GLOAD_LDS16(vsrc + ks0, &Vs[0][w * 1024]);
    GLOAD_LDS16(vsrc + ks0 + (size_t)8 * S_LEN, &Vs[0][w * 1024 + 512]);

    int p = 0;
    for (int ks = ks0; ks < ks1; ks += 64, p ^= 1) {
        __syncthreads();   // drains DMA for buf p; all waves done reading buf p^1
        if (ks + 64 < ks1) {
            const unsigned short* kn = ksrc + (size_t)(ks + 64) * DK_;
            const unsigned short* vn = vsrc + (ks + 64);
            GLOAD_LDS16(kn, &Ks[p ^ 1][w * 1024]);
            GLOAD_LDS16(kn + (size_t)8 * DK_, &Ks[p ^ 1][w * 1024 + 512]);
            GLOAD_LDS16(vn, &Vs[p ^ 1][w * 1024]);
            GLOAD_LDS16(vn + (size_t)8 * S_LEN, &Vs[p ^ 1][w * 1024 + 512]);
        }
        const unsigned short* KsT = &Ks[p][0];
        const unsigned short* VsT = &Vs[p][0];

#pragma unroll
        for (int kb = 0; kb < 2; kb++) {   // 32-key block
            // S^T for both q-tiles; each kf read feeds two MFMAs
            f32x16 stA = {0.f}, stB = {0.f};
            __builtin_amdgcn_s_setprio(1);
#pragma unroll
            for (int s = 0; s < 4; s++) {
                bf16x8 kf = *(const bf16x8*)&KsT[(kb * 32 + ln) * 64 + ((2 * s + hf) ^ swz) * 8];
                stA = __builtin_amdgcn_mfma_f32_32x32x16_bf16(kf, qfA[s], stA, 0, 0, 0);
                stB = __builtin_amdgcn_mfma_f32_32x32x16_bf16(kf, qfB[s], stB, 0, 0, 0);
            }
            __builtin_amdgcn_s_setprio(0);
            // softmax + pack, q-tile A
            bf16x8 b0A, b1A, b0B, b1B;
            {
                float e[16];
#pragma unroll
                for (int r = 0; r < 16; r++) e[r] = EXP2F(stA[r]);
                lsumA += ((e[0] + e[1]) + (e[2] + e[3])) + ((e[4] + e[5]) + (e[6] + e[7]))
                       + ((e[8] + e[9]) + (e[10] + e[11])) + ((e[12] + e[13]) + (e[14] + e[15]));
                unsigned int g[8];
#pragma unroll
                for (int gi = 0; gi < 8; gi++) g[gi] = pkbf(e[2 * gi], e[2 * gi + 1]);
                pl32swap(g[0], g[2]); pl32swap(g[1], g[3]);
                pl32swap(g[4], g[6]); pl32swap(g[5], g[7]);
                { uint4v t = {g[0], g[1], g[2], g[3]}; __builtin_memcpy(&b0A, &t, 16); }
                { uint4v t = {g[4], g[5], g[6], g[7]}; __builtin_memcpy(&b1A, &t, 16); }
            }
            // softmax + pack, q-tile B
            {
                float e[16];
#pragma unroll
                for (int r = 0; r < 16; r++) e[r] = EXP2F(stB[r]);
                lsumB += ((e[0] + e[1]) + (e[2] + e[3])) + ((e[4] + e[5]) + (e[6] + e[7]))
                       + ((e[8] + e[9]) + (e[10] + e[11])) + ((e[12] + e[13]) + (e[14] + e[15]));
                unsigned int g[8];
#pragma unroll
                for (int gi = 0; gi < 8; gi++) g[gi] = pkbf(e[2 * gi], e[2 * gi + 1]);
                pl32swap(g[0], g[2]); pl32swap(g[1], g[3]);
                pl32swap(g[4], g[6]); pl32swap(g[5], g[7]);
                { uint4v t = {g[0], g[1], g[2], g[3]}; __builtin_memcpy(&b0B, &t, 16); }
                { uint4v t = {g[4], g[5], g[6], g[7]}; __builtin_memcpy(&b1B, &t, 16); }
            }
            // O^T += V^T . P^T  — each vf read feeds both q-tiles
            __builtin_amdgcn_s_setprio(1);
#pragma unroll
            for (int dt = 0; dt < 2; dt++) {
                int s0 = kb * 2;
                bf16x8 vf0 = *(const bf16x8*)&VsT[(dt * 32 + ln) * 64 + ((2 * s0 + hf) ^ swz) * 8];
                bf16x8 vf1 = *(const bf16x8*)&VsT[(dt * 32 + ln) * 64 + ((2 * s0 + 2 + hf) ^ swz) * 8];
                oaccA[dt] = __builtin_amdgcn_mfma_f32_32x32x16_bf16(vf0, b0A, oaccA[dt], 0, 0, 0);
                oaccA[dt] = __builtin_amdgcn_mfma_f32_32x32x16_bf16(vf1, b1A, oaccA[dt], 0, 0, 0);
                oaccB[dt] = __builtin_amdgcn_mfma_f32_32x32x16_bf16(vf0, b0B, oaccB[dt], 0, 0, 0);
                oaccB[dt] = __builtin_amdgcn_mfma_f32_32x32x16_bf16(vf1, b1B, oaccB[dt], 0, 0, 0);
            }
            __builtin_amdgcn_s_setprio(0);
        }
    }

    // per-split denominators (both lane-halves combined)
    float ltotA = lsumA + __shfl_xor(lsumA, 32, 64);
    float ltotB = lsumB + __shfl_xor(lsumB, 32, 64);
    if (hf == 0) {
        lpart[(size_t)sp * (16 * S_LEN) + (size_t)bh * S_LEN + q0 + ln] = ltotA;
        lpart[(size_t)sp * (16 * S_LEN) + (size_t)bh * S_LEN + q0 + 32 + ln] = ltotB;
    }

    int bb = bh >> 3, hh = bh & 7;
    float* op = Opart + (size_t)sp * NTOK * DM_;
    int tokenA = bb * S_LEN + q0 + ln;
    int tokenB = tokenA + 32;
#pragma unroll
    for (int dt = 0; dt < 2; dt++)
#pragma unroll
        for (int gi = 0; gi < 8; gi++) {
            int d = dt * 32 + 2 * (gi & 1) + 8 * (gi >> 1) + 4 * hf;
            float2 oa; oa.x = oaccA[dt][2 * gi]; oa.y = oaccA[dt][2 * gi + 1];
            *(float2*)&op[(size_t)tokenA * DM_ + hh * DK_ + d] = oa;
            float2 ob; ob.x = oaccB[dt][2 * gi]; ob.y = oaccB[dt][2 * gi + 1];
            *(float2*)&op[(size_t)tokenB * DM_ + hh * DK_ + d] = ob;
        }
}

// ---------- merge NSP key-split partials -> normalized bf16 Ao ----------
template <int NSP>
__global__ __launch_bounds__(256) void merge_split(const float* __restrict__ Opart,
                                                   const float* __restrict__ lpart,
                                                   unsigned short* __restrict__ Ao) {
    size_t e = ((size_t)blockIdx.x * 256 + threadIdx.x) * 4;   // 4 f32 elems, same head
    int token = (int)(e >> 9);
    int c = (int)(e & 511);
    int hh = c >> 6;
    int bb = token >> 12, s = token & 4095;
    size_t li = (size_t)(bb * NHEAD + hh) * S_LEN + s;
    float ltot = 0.f;
#pragma unroll
    for (int j = 0; j < NSP; j++) ltot += lpart[(size_t)j * (16 * S_LEN) + li];
    float inv = 1.0f / ltot;
    float4 a = *(const float4*)&Opart[e];
#pragma unroll
    for (int j = 1; j < NSP; j++) {
        float4 b = *(const float4*)&Opart[(size_t)j * NTOK * DM_ + e];
        a.x += b.x; a.y += b.y; a.z += b.z; a.w += b.w;
    }
    uint2 o;
    o.x = pkbf(a.x * inv, a.y * inv);
    o.y = pkbf(a.z * inv, a.w * inv);
    *(uint2*)&Ao[e] = o;
}

// ---------- output GEMM: out = Ao(bf16)@Wo + bo, fp32 out ----------
__global__ __launch_bounds__(256) void out_gemm(const unsigned short* __restrict__ A,
                                                const unsigned short* __restrict__ Wt,
                                                const float* __restrict__ bias, float* __restrict__ out) {
    __shared__ unsigned short As[128 * 40];
    __shared__ unsigned short Bs[128 * 40];
    int tid = threadIdx.x;
    int n0 = blockIdx.x * 128, m0 = blockIdx.y * 128;
    int w = tid >> 6, lane = tid & 63;
    int ln = lane & 15, qd = lane >> 4;
    int mb = (w >> 1) * 64, nb = (w & 1) * 64;

    f32x4 acc[4][4];
#pragma unroll
    for (int i = 0; i < 4; i++)
#pragma unroll
        for (int j = 0; j < 4; j++) { f32x4 z = {0.f, 0.f, 0.f, 0.f}; acc[i][j] = z; }

    for (int kk = 0; kk < DM_; kk += 32) {
        __syncthreads();
#pragma unroll
        for (int i = 0; i < 2; i++) {
            int idx = i * 256 + tid;
            int row = idx >> 2, k8 = (idx & 3) * 8;
            uint4 va = *(const uint4*)&A[(size_t)(m0 + row) * DM_ + kk + k8];
            *(uint4*)&As[row * 40 + k8] = va;
            uint4 vb = *(const uint4*)&Wt[(size_t)(n0 + row) * DM_ + kk + k8];
            *(uint4*)&Bs[row * 40 + k8] = vb;
        }
        __syncthreads();
        bf16x8 af[4], bf[4];
#pragma unroll
        for (int mt = 0; mt < 4; mt++) af[mt] = *(const bf16x8*)&As[(mb + mt * 16 + ln) * 40 + qd * 8];
#pragma unroll
        for (int nt = 0; nt < 4; nt++) bf[nt] = *(const bf16x8*)&Bs[(nb + nt * 16 + ln) * 40 + qd * 8];
#pragma unroll
        for (int mt = 0; mt < 4; mt++)
#pragma unroll
            for (int nt = 0; nt < 4; nt++)
                acc[mt][nt] = __builtin_amdgcn_mfma_f32_16x16x32_bf16(af[mt], bf[nt], acc[mt][nt], 0, 0, 0);
    }

    float bv[4];
#pragma unroll
    for (int nt = 0; nt < 4; nt++) bv[nt] = bias[n0 + nb + nt * 16 + ln];
#pragma unroll
    for (int mt = 0; mt < 4; mt++) {
        int mrow0 = m0 + mb + mt * 16 + qd * 4;
#pragma unroll
        for (int nt = 0; nt < 4; nt++) {
            int ncol = n0 + nb + nt * 16 + ln;
#pragma unroll
            for (int r = 0; r < 4; r++)
                out[(size_t)(mrow0 + r) * DM_ + ncol] = acc[mt][nt][r] + bv[nt];
        }
    }
}

extern "C" void kernel_launch(void* const* d_in, const int* in_sizes, int n_in,
                              void* d_out, int out_size, void* d_ws, size_t ws_size,
                              hipStream_t stream) {
    const float* q  = (const float*)d_in[0];
    const float* k  = (const float*)d_in[1];
    const float* v  = (const float*)d_in[2];
    const float* Wq = (const float*)d_in[3];
    const float* bq = (const float*)d_in[4];
    const float* Wk = (const float*)d_in[5];
    const float* bk = (const float*)d_in[6];
    const float* Wv = (const float*)d_in[7];
    const float* bv = (const float*)d_in[8];
    const float* Wo = (const float*)d_in[9];
    const float* bo = (const float*)d_in[10];
    float* out = (float*)d_out;

    unsigned short* Wt  = (unsigned short*)d_ws;
    unsigned short* Qh  = Wt + (size_t)4 * DM_ * DM_;
    unsigned short* Kh  = Qh + (size_t)NTOK * DM_;
    unsigned short* VhT = Kh + (size_t)NTOK * DM_;
    unsigned short* tail = VhT + (size_t)NTOK * DM_;

    size_t head_b  = ((size_t)4 * DM_ * DM_ + (size_t)3 * NTOK * DM_) * 2;
    size_t opart_b4 = (size_t)4 * NTOK * DM_ * 4;
    size_t lpart_b4 = (size_t)4 * 16 * S_LEN * 4;
    size_t opart_b2 = (size_t)2 * NTOK * DM_ * 4;
    size_t lpart_b2 = (size_t)2 * 16 * S_LEN * 4;
    size_t ao_b     = (size_t)NTOK * DM_ * 2;
    size_t need_sp4 = head_b + opart_b4 + lpart_b4 + ao_b;
    size_t need_sp2 = head_b + opart_b2 + lpart_b2 + ao_b;
    size_t need_bf  = ((size_t)4 * DM_ * DM_ + (size_t)6 * NTOK * DM_) * 2;

    wtrans<<<dim3(8, 8, 4), 256, 0, stream>>>(Wq, Wk, Wv, Wo, Wt);
    if (ws_size >= need_sp4) {
        // tail layout: [Opart 4x f32][lpart 4x][Ao bf16]; Xbf aliases head of Opart
        float* Opart = (float*)tail;
        float* lpart = Opart + (size_t)4 * NTOK * DM_;
        unsigned short* Ao = (unsigned short*)(lpart + (size_t)4 * 16 * S_LEN);
        unsigned short* Xbf = tail;
        xcvt<<<dim3(4096, 3), 256, 0, stream>>>(q, k, v, Xbf);
        qkv_bf<<<dim3(4, 64, 3), 256, 0, stream>>>(Xbf, Wt, bq, bk, bv, Qh, Kh, VhT);
        flash_attn_sp4<<<dim3(1024), 256, 0, stream>>>(Qh, Kh, VhT, Opart, lpart);
        merge_split<4><<<dim3(4096), 256, 0, stream>>>(Opart, lpart, Ao);
        out_gemm<<<dim3(4, 64), 256, 0, stream>>>(Ao, Wt + (size_t)3 * DM_ * DM_, bo, out);
    } else if (ws_size >= need_sp2) {
        float* Opart = (float*)tail;
        float* lpart = Opart + (size_t)2 * NTOK * DM_;
        unsigned short* Ao = (unsigned short*)(lpart + (size_t)2 * 16 * S_LEN);
        unsigned short* Xbf = tail;
        xcvt<<<dim3(4096, 3), 256, 0, stream>>>(q, k, v, Xbf);
        qkv_bf<<<dim3(4, 64, 3), 256, 0, stream>>>(Xbf, Wt, bq, bk, bv, Qh, Kh, VhT);
        flash_attn_sp<<<dim3(1024), 256, 0, stream>>>(Qh, Kh, VhT, Opart, lpart);
        merge_split<2><<<dim3(4096), 256, 0, stream>>>(Opart, lpart, Ao);
        out_gemm<<<dim3(4, 64), 256, 0, stream>>>(Ao, Wt + (size_t)3 * DM_ * DM_, bo, out);
    } else if (ws_size >= need_bf) {
        unsigned short* Xbf = tail;   // Ao aliases Xbf head (Xbf dead before flash writes Ao)
        unsigned short* Ao = tail;
        xcvt<<<dim3(4096, 3), 256, 0, stream>>>(q, k, v, Xbf);
        qkv_bf<<<dim3(4, 64, 3), 256, 0, stream>>>(Xbf, Wt, bq, bk, bv, Qh, Kh, VhT);
        flash_attn<<<dim3(512), 256, 0, stream>>>(Qh, Kh, VhT, Ao);
        out_gemm<<<dim3(4, 64), 256, 0, stream>>>(Ao, Wt + (size_t)3 * DM_ * DM_, bo, out);
    } else {
        unsigned short* Ao = tail;
        qkv_proj<<<dim3(4, 64, 3), 256, 0, stream>>>(q, k, v, Wt, bq, bk, bv, Qh, Kh, VhT);
        flash_attn<<<dim3(512), 256, 0, stream>>>(Qh, Kh, VhT, Ao);
        out_gemm<<<dim3(4, 64), 256, 0, stream>>>(Ao, Wt + (size_t)3 * DM_ * DM_, bo, out);
    }
}

// Round 4
// 260.854 us; speedup vs baseline: 1.4742x; 1.4742x over previous
//
#include <hip/hip_runtime.h>
#include <hip/hip_bf16.h>

#define NHEAD 8
#define DK_ 64
#define DM_ 512
#define S_LEN 4096
#define NTOK 8192

typedef __bf16 bf16x8 __attribute__((ext_vector_type(8)));
typedef float f32x4 __attribute__((ext_vector_type(4)));
typedef float f32x16 __attribute__((ext_vector_type(16)));
typedef unsigned int uint4v __attribute__((ext_vector_type(4)));

__device__ __forceinline__ unsigned short f2bf(float f) {
    union { float f; unsigned u; } x; x.f = f;
    unsigned u = x.u;
    u += 0x7FFFu + ((u >> 16) & 1u);   // round-to-nearest-even (inputs finite)
    return (unsigned short)(u >> 16);
}

// packed f32x2 -> bf16x2 (gfx950 HW op when available; RNE either way)
#if __has_builtin(__builtin_amdgcn_cvt_pk_bf16_f32)
__device__ __forceinline__ unsigned int pkbf(float a, float b) {
    auto r = __builtin_amdgcn_cvt_pk_bf16_f32(a, b);
    unsigned int u; __builtin_memcpy(&u, &r, 4); return u;
}
#else
__device__ __forceinline__ unsigned int pkbf(float a, float b) {
    return (unsigned)f2bf(a) | ((unsigned)f2bf(b) << 16);
}
#endif

#if __has_builtin(__builtin_amdgcn_exp2f)
#define EXP2F(x) __builtin_amdgcn_exp2f(x)
#else
#define EXP2F(x) exp2f(x)
#endif

// lane-half <-> reg exchange: new_a = {a_lo, b_lo}, new_b = {a_hi, b_hi}
#if __has_builtin(__builtin_amdgcn_permlane32_swap)
__device__ __forceinline__ void pl32swap(unsigned int& a, unsigned int& b) {
    auto r = __builtin_amdgcn_permlane32_swap(a, b, false, false);
    a = r[0]; b = r[1];
}
#else
__device__ __forceinline__ void pl32swap(unsigned int& a, unsigned int& b) {
    int lane = threadIdx.x & 63;
    unsigned int ax = __shfl_xor((int)a, 32, 64);
    unsigned int bx = __shfl_xor((int)b, 32, 64);
    unsigned int na = (lane < 32) ? a : bx;
    unsigned int nb = (lane < 32) ? ax : b;
    a = na; b = nb;
}
#endif

// async global->LDS, 16B per lane; LDS dest = wave-uniform base + lane*16
#define GLOAD_LDS16(gptr, ldsbase) \
    __builtin_amdgcn_global_load_lds((const __attribute__((address_space(1))) unsigned int*)(gptr), \
                                     (__attribute__((address_space(3))) unsigned int*)(ldsbase), 16, 0, 0)

// ---------- xcvt: Xbf[z][tok][dm] = bf16(x_z) ----------
__global__ __launch_bounds__(256) void xcvt(const float* __restrict__ q, const float* __restrict__ k,
                                            const float* __restrict__ v, unsigned short* __restrict__ Xbf) {
    int z = blockIdx.y;
    const float* X = (z == 0) ? q : (z == 1) ? k : v;
    size_t off = (size_t)blockIdx.x * 1024 + threadIdx.x * 4;
    float4 val = *(const float4*)&X[off];
    uint2 o; o.x = pkbf(val.x, val.y); o.y = pkbf(val.z, val.w);
    *(uint2*)&Xbf[(size_t)z * NTOK * DM_ + off] = o;
}

// ---------- kernel 0: Wt[z][n][k] = bf16(W_z[k][n]) ----------
__global__ __launch_bounds__(256) void wtrans(const float* __restrict__ Wq, const float* __restrict__ Wk,
                                              const float* __restrict__ Wv, const float* __restrict__ Wo,
                                              unsigned short* __restrict__ Wt) {
    int z = blockIdx.z;
    const float* W = (z == 0) ? Wq : (z == 1) ? Wk : (z == 2) ? Wv : Wo;
    unsigned short* out = Wt + (size_t)z * DM_ * DM_;
    __shared__ float t[64][65];
    int bn = blockIdx.x * 64, bk = blockIdx.y * 64;
    int tid = threadIdx.x;
    int r0 = tid >> 4, c4 = (tid & 15) * 4;
#pragma unroll
    for (int i = 0; i < 4; i++) {
        int r = r0 + i * 16;
        float4 v = *(const float4*)&W[(size_t)(bk + r) * DM_ + bn + c4];
        t[r][c4] = v.x; t[r][c4 + 1] = v.y; t[r][c4 + 2] = v.z; t[r][c4 + 3] = v.w;
    }
    __syncthreads();
    int n0 = tid >> 4, k4 = (tid & 15) * 4;
#pragma unroll
    for (int i = 0; i < 4; i++) {
        int n = n0 + i * 16;
        ushort4 o;
        o.x = f2bf(t[k4 + 0][n]); o.y = f2bf(t[k4 + 1][n]);
        o.z = f2bf(t[k4 + 2][n]); o.w = f2bf(t[k4 + 3][n]);
        *(ushort4*)&out[(size_t)(bn + n) * DM_ + bk + k4] = o;
    }
}

// shared epilogue for projection GEMMs
__device__ __forceinline__ void proj_epilogue(int z, f32x4 (&acc)[4][4], const float* bias,
                                              unsigned short* out, float scale,
                                              int m0, int n0, int mb, int nb, int ln, int qd) {
    float bvv[4];
#pragma unroll
    for (int nt = 0; nt < 4; nt++) bvv[nt] = bias[n0 + nb + nt * 16 + ln];
#pragma unroll
    for (int mt = 0; mt < 4; mt++) {
        int mrow0 = m0 + mb + mt * 16 + qd * 4;
        int b = mrow0 >> 12, s = mrow0 & 4095;
#pragma unroll
        for (int nt = 0; nt < 4; nt++) {
            int ncol = n0 + nb + nt * 16 + ln;
            int h = ncol >> 6, d = ncol & 63;
            if (z == 2) {
                uint2 o;
                o.x = pkbf((acc[mt][nt][0] + bvv[nt]) * scale, (acc[mt][nt][1] + bvv[nt]) * scale);
                o.y = pkbf((acc[mt][nt][2] + bvv[nt]) * scale, (acc[mt][nt][3] + bvv[nt]) * scale);
                *(uint2*)&out[((size_t)(b * NHEAD + h) * DK_ + d) * S_LEN + s] = o;
            } else {
#pragma unroll
                for (int r = 0; r < 4; r++)
                    out[((size_t)(b * NHEAD + h) * S_LEN + (s + r)) * DK_ + d] =
                        f2bf((acc[mt][nt][r] + bvv[nt]) * scale);
            }
        }
    }
}

// ---------- fused QKV projection from pre-converted bf16 X ----------
__global__ __launch_bounds__(256, 3) void qkv_bf(const unsigned short* __restrict__ Xbf,
                                                 const unsigned short* __restrict__ Wt,
                                                 const float* __restrict__ bq, const float* __restrict__ bk,
                                                 const float* __restrict__ bv,
                                                 unsigned short* __restrict__ Qh, unsigned short* __restrict__ Kh,
                                                 unsigned short* __restrict__ VhT) {
    int z = blockIdx.z;
    const unsigned short* X = Xbf + (size_t)z * NTOK * DM_;
    const unsigned short* W = Wt + (size_t)z * DM_ * DM_;
    const float* bias = (z == 0) ? bq : (z == 1) ? bk : bv;
    unsigned short* out = (z == 0) ? Qh : (z == 1) ? Kh : VhT;
    float scale = (z == 0) ? 0.125f * 1.44269504f : 1.0f;

    __shared__ unsigned short As[128 * 40];
    __shared__ unsigned short Bs[128 * 40];
    int tid = threadIdx.x;
    int n0 = blockIdx.x * 128, m0 = blockIdx.y * 128;
    int w = tid >> 6, lane = tid & 63;
    int ln = lane & 15, qd = lane >> 4;
    int mb = (w >> 1) * 64, nb = (w & 1) * 64;

    f32x4 acc[4][4];
#pragma unroll
    for (int i = 0; i < 4; i++)
#pragma unroll
        for (int j = 0; j < 4; j++) { f32x4 zz = {0.f, 0.f, 0.f, 0.f}; acc[i][j] = zz; }

    for (int kk = 0; kk < DM_; kk += 32) {
        __syncthreads();
#pragma unroll
        for (int i = 0; i < 2; i++) {
            int idx = i * 256 + tid;
            int row = idx >> 2, k8 = (idx & 3) * 8;
            uint4 va = *(const uint4*)&X[(size_t)(m0 + row) * DM_ + kk + k8];
            *(uint4*)&As[row * 40 + k8] = va;
            uint4 vb = *(const uint4*)&W[(size_t)(n0 + row) * DM_ + kk + k8];
            *(uint4*)&Bs[row * 40 + k8] = vb;
        }
        __syncthreads();
        bf16x8 af[4], bf[4];
#pragma unroll
        for (int mt = 0; mt < 4; mt++) af[mt] = *(const bf16x8*)&As[(mb + mt * 16 + ln) * 40 + qd * 8];
#pragma unroll
        for (int nt = 0; nt < 4; nt++) bf[nt] = *(const bf16x8*)&Bs[(nb + nt * 16 + ln) * 40 + qd * 8];
#pragma unroll
        for (int mt = 0; mt < 4; mt++)
#pragma unroll
            for (int nt = 0; nt < 4; nt++)
                acc[mt][nt] = __builtin_amdgcn_mfma_f32_16x16x32_bf16(af[mt], bf[nt], acc[mt][nt], 0, 0, 0);
    }
    proj_epilogue(z, acc, bias, out, scale, m0, n0, mb, nb, ln, qd);
}

// ---------- fallback fused QKV projection from fp32 X (small ws) ----------
__global__ __launch_bounds__(256, 3) void qkv_proj(const float* __restrict__ xq, const float* __restrict__ xk,
                                                   const float* __restrict__ xv, const unsigned short* __restrict__ Wt,
                                                   const float* __restrict__ bq, const float* __restrict__ bk,
                                                   const float* __restrict__ bv,
                                                   unsigned short* __restrict__ Qh, unsigned short* __restrict__ Kh,
                                                   unsigned short* __restrict__ VhT) {
    int z = blockIdx.z;
    const float* X = (z == 0) ? xq : (z == 1) ? xk : xv;
    const unsigned short* W = Wt + (size_t)z * DM_ * DM_;
    const float* bias = (z == 0) ? bq : (z == 1) ? bk : bv;
    unsigned short* out = (z == 0) ? Qh : (z == 1) ? Kh : VhT;
    float scale = (z == 0) ? 0.125f * 1.44269504f : 1.0f;

    __shared__ unsigned short As[128 * 40];
    __shared__ unsigned short Bs[128 * 40];
    int tid = threadIdx.x;
    int n0 = blockIdx.x * 128, m0 = blockIdx.y * 128;
    int w = tid >> 6, lane = tid & 63;
    int ln = lane & 15, qd = lane >> 4;
    int mb = (w >> 1) * 64, nb = (w & 1) * 64;

    f32x4 acc[4][4];
#pragma unroll
    for (int i = 0; i < 4; i++)
#pragma unroll
        for (int j = 0; j < 4; j++) { f32x4 zz = {0.f, 0.f, 0.f, 0.f}; acc[i][j] = zz; }

    for (int kk = 0; kk < DM_; kk += 32) {
        __syncthreads();
#pragma unroll
        for (int i = 0; i < 4; i++) {
            int idx = i * 256 + tid;
            int row = idx >> 3, k4 = (idx & 7) * 4;
            float4 v = *(const float4*)&X[(size_t)(m0 + row) * DM_ + kk + k4];
            uint2 o; o.x = pkbf(v.x, v.y); o.y = pkbf(v.z, v.w);
            *(uint2*)&As[row * 40 + k4] = o;
        }
#pragma unroll
        for (int i = 0; i < 2; i++) {
            int idx = i * 256 + tid;
            int row = idx >> 2, k8 = (idx & 3) * 8;
            uint4 v = *(const uint4*)&W[(size_t)(n0 + row) * DM_ + kk + k8];
            *(uint4*)&Bs[row * 40 + k8] = v;
        }
        __syncthreads();
        bf16x8 af[4], bf[4];
#pragma unroll
        for (int mt = 0; mt < 4; mt++) af[mt] = *(const bf16x8*)&As[(mb + mt * 16 + ln) * 40 + qd * 8];
#pragma unroll
        for (int nt = 0; nt < 4; nt++) bf[nt] = *(const bf16x8*)&Bs[(nb + nt * 16 + ln) * 40 + qd * 8];
#pragma unroll
        for (int mt = 0; mt < 4; mt++)
#pragma unroll
            for (int nt = 0; nt < 4; nt++)
                acc[mt][nt] = __builtin_amdgcn_mfma_f32_16x16x32_bf16(af[mt], bf[nt], acc[mt][nt], 0, 0, 0);
    }
    proj_epilogue(z, acc, bias, out, scale, m0, n0, mb, nb, ln, qd);
}

// ---------- flash attention (legacy single-pass, small-ws fallback) ----------
__global__ __launch_bounds__(256, 2) void flash_attn(const unsigned short* __restrict__ Qh,
                                                     const unsigned short* __restrict__ Kh,
                                                     const unsigned short* __restrict__ VhT,
                                                     unsigned short* __restrict__ Ao) {
    __shared__ unsigned short Ks[2][64 * 64];     // 16 KB
    __shared__ unsigned short Vs[2][64 * 64];     // 16 KB
    int i = blockIdx.x;
    int bh = (i & 7) + 8 * ((i >> 3) & 1);
    int qb = i >> 4;
    int tid = threadIdx.x;
    int w = tid >> 6, lane = tid & 63;
    int ln = lane & 31, hf = lane >> 5;
    int swz = ln & 7;
    int q0 = qb * 128 + w * 32;
    const unsigned short* Qp = Qh + (size_t)bh * S_LEN * DK_;
    const unsigned short* Kp = Kh + (size_t)bh * S_LEN * DK_;
    const unsigned short* Vp = VhT + (size_t)bh * DK_ * S_LEN;

    int sr = lane >> 3;
    int sc = (lane & 7) ^ sr;
    const unsigned short* ksrc = Kp + (size_t)(w * 16 + sr) * DK_ + sc * 8;
    const unsigned short* vsrc = Vp + (size_t)(w * 16 + sr) * S_LEN + sc * 8;

    bf16x8 qf[4];
#pragma unroll
    for (int s = 0; s < 4; s++)
        qf[s] = *(const bf16x8*)&Qp[(size_t)(q0 + ln) * DK_ + s * 16 + hf * 8];

    f32x16 oacc[2];
    { f32x16 z = {0.f}; oacc[0] = z; oacc[1] = z; }
    float lsum = 0.f;

    GLOAD_LDS16(ksrc, &Ks[0][w * 1024]);
    GLOAD_LDS16(ksrc + (size_t)8 * DK_, &Ks[0][w * 1024 + 512]);
    GLOAD_LDS16(vsrc, &Vs[0][w * 1024]);
    GLOAD_LDS16(vsrc + (size_t)8 * S_LEN, &Vs[0][w * 1024 + 512]);

    int p = 0;
    for (int ks = 0; ks < S_LEN; ks += 64, p ^= 1) {
        __syncthreads();
        if (ks + 64 < S_LEN) {
            const unsigned short* kn = ksrc + (size_t)(ks + 64) * DK_;
            const unsigned short* vn = vsrc + (ks + 64);
            GLOAD_LDS16(kn, &Ks[p ^ 1][w * 1024]);
            GLOAD_LDS16(kn + (size_t)8 * DK_, &Ks[p ^ 1][w * 1024 + 512]);
            GLOAD_LDS16(vn, &Vs[p ^ 1][w * 1024]);
            GLOAD_LDS16(vn + (size_t)8 * S_LEN, &Vs[p ^ 1][w * 1024 + 512]);
        }
        const unsigned short* KsT = &Ks[p][0];
        const unsigned short* VsT = &Vs[p][0];

#pragma unroll
        for (int kb = 0; kb < 2; kb++) {
            f32x16 st = {0.f};
#pragma unroll
            for (int s = 0; s < 4; s++) {
                bf16x8 kf = *(const bf16x8*)&KsT[(kb * 32 + ln) * 64 + ((2 * s + hf) ^ swz) * 8];
                st = __builtin_amdgcn_mfma_f32_32x32x16_bf16(kf, qf[s], st, 0, 0, 0);
            }
            float e[16];
#pragma unroll
            for (int r = 0; r < 16; r++) e[r] = EXP2F(st[r]);
            lsum += ((e[0] + e[1]) + (e[2] + e[3])) + ((e[4] + e[5]) + (e[6] + e[7]))
                  + ((e[8] + e[9]) + (e[10] + e[11])) + ((e[12] + e[13]) + (e[14] + e[15]));
            unsigned int g[8];
#pragma unroll
            for (int gi = 0; gi < 8; gi++) g[gi] = pkbf(e[2 * gi], e[2 * gi + 1]);
            pl32swap(g[0], g[2]); pl32swap(g[1], g[3]);
            pl32swap(g[4], g[6]); pl32swap(g[5], g[7]);
            bf16x8 b0, b1;
            { uint4v t = {g[0], g[1], g[2], g[3]}; __builtin_memcpy(&b0, &t, 16); }
            { uint4v t = {g[4], g[5], g[6], g[7]}; __builtin_memcpy(&b1, &t, 16); }
#pragma unroll
            for (int dt = 0; dt < 2; dt++) {
                int s0 = kb * 2;
                bf16x8 vf0 = *(const bf16x8*)&VsT[(dt * 32 + ln) * 64 + ((2 * s0 + hf) ^ swz) * 8];
                bf16x8 vf1 = *(const bf16x8*)&VsT[(dt * 32 + ln) * 64 + ((2 * s0 + 2 + hf) ^ swz) * 8];
                oacc[dt] = __builtin_amdgcn_mfma_f32_32x32x16_bf16(vf0, b0, oacc[dt], 0, 0, 0);
                oacc[dt] = __builtin_amdgcn_mfma_f32_32x32x16_bf16(vf1, b1, oacc[dt], 0, 0, 0);
            }
        }
    }

    float ltot = lsum + __shfl_xor(lsum, 32, 64);
    float inv = 1.0f / ltot;

    int bb = bh >> 3, hh = bh & 7;
    int token = bb * S_LEN + q0 + ln;
#pragma unroll
    for (int dt = 0; dt < 2; dt++)
#pragma unroll
        for (int gi = 0; gi < 8; gi++) {
            int d = dt * 32 + 2 * (gi & 1) + 8 * (gi >> 1) + 4 * hf;
            unsigned int o = pkbf(oacc[dt][2 * gi] * inv, oacc[dt][2 * gi + 1] * inv);
            *(unsigned int*)&Ao[(size_t)token * DM_ + hh * DK_ + d] = o;
        }
}

// ---------- split-K flash attention (32 q/wave, 2-way key split) ----------
// Round-1 proven shape: 99.5 us. Kept as mid-tier fallback.
__global__ __launch_bounds__(256, 4) void flash_attn_sp(const unsigned short* __restrict__ Qh,
                                                        const unsigned short* __restrict__ Kh,
                                                        const unsigned short* __restrict__ VhT,
                                                        float* __restrict__ Opart,
                                                        float* __restrict__ lpart) {
    __shared__ unsigned short Ks[2][64 * 64];
    __shared__ unsigned short Vs[2][64 * 64];
    int i = blockIdx.x;
    int bh = (i & 7) + 8 * ((i >> 3) & 1);
    int qb = (i >> 4) & 31;
    int sp = i >> 9;
    int ks0 = sp * (S_LEN / 2);
    int ks1 = ks0 + (S_LEN / 2);
    int tid = threadIdx.x;
    int w = tid >> 6, lane = tid & 63;
    int ln = lane & 31, hf = lane >> 5;
    int swz = ln & 7;
    int q0 = qb * 128 + w * 32;
    const unsigned short* Qp = Qh + (size_t)bh * S_LEN * DK_;
    const unsigned short* Kp = Kh + (size_t)bh * S_LEN * DK_;
    const unsigned short* Vp = VhT + (size_t)bh * DK_ * S_LEN;

    int sr = lane >> 3;
    int sc = (lane & 7) ^ sr;
    const unsigned short* ksrc = Kp + (size_t)(w * 16 + sr) * DK_ + sc * 8;
    const unsigned short* vsrc = Vp + (size_t)(w * 16 + sr) * S_LEN + sc * 8;

    bf16x8 qf[4];
#pragma unroll
    for (int s = 0; s < 4; s++)
        qf[s] = *(const bf16x8*)&Qp[(size_t)(q0 + ln) * DK_ + s * 16 + hf * 8];

    f32x16 oacc[2];
    { f32x16 z = {0.f}; oacc[0] = z; oacc[1] = z; }
    float lsum = 0.f;

    GLOAD_LDS16(ksrc + (size_t)ks0 * DK_, &Ks[0][w * 1024]);
    GLOAD_LDS16(ksrc + (size_t)(ks0 + 8) * DK_, &Ks[0][w * 1024 + 512]);
    GLOAD_LDS16(vsrc + ks0, &Vs[0][w * 1024]);
    GLOAD_LDS16(vsrc + ks0 + (size_t)8 * S_LEN, &Vs[0][w * 1024 + 512]);

    int p = 0;
    for (int ks = ks0; ks < ks1; ks += 64, p ^= 1) {
        __syncthreads();
        if (ks + 64 < ks1) {
            const unsigned short* kn = ksrc + (size_t)(ks + 64) * DK_;
            const unsigned short* vn = vsrc + (ks + 64);
            GLOAD_LDS16(kn, &Ks[p ^ 1][w * 1024]);
            GLOAD_LDS16(kn + (size_t)8 * DK_, &Ks[p ^ 1][w * 1024 + 512]);
            GLOAD_LDS16(vn, &Vs[p ^ 1][w * 1024]);
            GLOAD_LDS16(vn + (size_t)8 * S_LEN, &Vs[p ^ 1][w * 1024 + 512]);
        }
        const unsigned short* KsT = &Ks[p][0];
        const unsigned short* VsT = &Vs[p][0];

#pragma unroll
        for (int kb = 0; kb < 2; kb++) {
            f32x16 st = {0.f};
#pragma unroll
            for (int s = 0; s < 4; s++) {
                bf16x8 kf = *(const bf16x8*)&KsT[(kb * 32 + ln) * 64 + ((2 * s + hf) ^ swz) * 8];
                st = __builtin_amdgcn_mfma_f32_32x32x16_bf16(kf, qf[s], st, 0, 0, 0);
            }
            float e[16];
#pragma unroll
            for (int r = 0; r < 16; r++) e[r] = EXP2F(st[r]);
            lsum += ((e[0] + e[1]) + (e[2] + e[3])) + ((e[4] + e[5]) + (e[6] + e[7]))
                  + ((e[8] + e[9]) + (e[10] + e[11])) + ((e[12] + e[13]) + (e[14] + e[15]));
            unsigned int g[8];
#pragma unroll
            for (int gi = 0; gi < 8; gi++) g[gi] = pkbf(e[2 * gi], e[2 * gi + 1]);
            pl32swap(g[0], g[2]); pl32swap(g[1], g[3]);
            pl32swap(g[4], g[6]); pl32swap(g[5], g[7]);
            bf16x8 b0, b1;
            { uint4v t = {g[0], g[1], g[2], g[3]}; __builtin_memcpy(&b0, &t, 16); }
            { uint4v t = {g[4], g[5], g[6], g[7]}; __builtin_memcpy(&b1, &t, 16); }
#pragma unroll
            for (int dt = 0; dt < 2; dt++) {
                int s0 = kb * 2;
                bf16x8 vf0 = *(const bf16x8*)&VsT[(dt * 32 + ln) * 64 + ((2 * s0 + hf) ^ swz) * 8];
                bf16x8 vf1 = *(const bf16x8*)&VsT[(dt * 32 + ln) * 64 + ((2 * s0 + 2 + hf) ^ swz) * 8];
                oacc[dt] = __builtin_amdgcn_mfma_f32_32x32x16_bf16(vf0, b0, oacc[dt], 0, 0, 0);
                oacc[dt] = __builtin_amdgcn_mfma_f32_32x32x16_bf16(vf1, b1, oacc[dt], 0, 0, 0);
            }
        }
    }

    float ltot = lsum + __shfl_xor(lsum, 32, 64);
    if (hf == 0)
        lpart[(size_t)sp * (16 * S_LEN) + (size_t)bh * S_LEN + q0 + ln] = ltot;

    int bb = bh >> 3, hh = bh & 7;
    int token = bb * S_LEN + q0 + ln;
    float* op = Opart + (size_t)sp * NTOK * DM_;
#pragma unroll
    for (int dt = 0; dt < 2; dt++)
#pragma unroll
        for (int gi = 0; gi < 8; gi++) {
            int d = dt * 32 + 2 * (gi & 1) + 8 * (gi >> 1) + 4 * hf;
            float2 o; o.x = oacc[dt][2 * gi]; o.y = oacc[dt][2 * gi + 1];
            *(float2*)&op[(size_t)token * DM_ + hh * DK_ + d] = o;
        }
}

// ---------- split-K flash kv32: 32 q/wave, KVBLK=32, 4-way split ----------
// Round-3 post-mortem: forcing 4 waves/EU on the 64q/wave state spilled (VGPR
// 64 << 170 live) -> 900MB scratch traffic. Occupancy is the only lever that
// has moved this kernel (2->4 waves/SIMD = -8%), so: keep the proven 32q/wave
// 64-VGPR state and DOUBLE resident waves again via smaller LDS footprint.
// KVBLK=32 double-buffered: Ks 2x4KB + Vs 2x4KB = 16KB/block -> 8 blocks/CU
// (grid 2048 = 16bh x 32qb x 4sp) = 32 waves/CU = 8 waves/SIMD at VGPR<=64.
// Per-wave DMA: 1 K-gload + 1 V-gload per 32-key tile; prefetch kept.
__global__ __launch_bounds__(256, 4) void flash_attn_kv32(const unsigned short* __restrict__ Qh,
                                                          const unsigned short* __restrict__ Kh,
                                                          const unsigned short* __restrict__ VhT,
                                                          float* __restrict__ Opart,
                                                          float* __restrict__ lpart) {
    __shared__ unsigned short Ks[2][32 * 64];     // 4 KB per buf: 32 keys x 64 dk
    __shared__ unsigned short Vs[2][64 * 32];     // 4 KB per buf: 64 d x 32 keys
    int i = blockIdx.x;
    int bh = i & 15;
    int qb = (i >> 4) & 31;                        // 32 q-blocks of 128
    int sp = i >> 9;                               // 0..3 key-split quarter
    int ks0 = sp * (S_LEN / 4);
    int ks1 = ks0 + (S_LEN / 4);
    int tid = threadIdx.x;
    int w = tid >> 6, lane = tid & 63;
    int ln = lane & 31, hf = lane >> 5;
    int swz = ln & 7;
    int q0 = qb * 128 + w * 32;
    const unsigned short* Qp = Qh + (size_t)bh * S_LEN * DK_;
    const unsigned short* Kp = Kh + (size_t)bh * S_LEN * DK_;
    const unsigned short* Vp = VhT + (size_t)bh * DK_ * S_LEN;

    // K staging: wave w stages key-rows w*8..w*8+7 (1 gload = 1KB).
    // lane l -> row w*8 + (l>>3), chunk-slot l&7; slot x holds global chunk
    // x^(row&7) (involution; row&7 == l>>3 here since w*8 is 8-aligned).
    int krow = lane >> 3;                          // 0..7 within slab
    int kchunk = (lane & 7) ^ krow;
    const unsigned short* ksrc = Kp + (size_t)(w * 8 + krow) * DK_ + kchunk * 8;
    // V staging: wave w stages d-rows w*16..w*16+15 (1 gload = 1KB, 64B rows).
    // lane l -> row w*16 + (l>>2), slot l&3; slot x holds chunk x^(row&3).
    int vrow = lane >> 2;                          // 0..15 within slab
    int vchunk = (lane & 3) ^ (vrow & 3);
    const unsigned short* vsrc = Vp + (size_t)(w * 16 + vrow) * S_LEN + vchunk * 8;

    bf16x8 qf[4];
#pragma unroll
    for (int s = 0; s < 4; s++)
        qf[s] = *(const bf16x8*)&Qp[(size_t)(q0 + ln) * DK_ + s * 16 + hf * 8];

    f32x16 oacc[2];   // O^T: [dt] 32 d x 32 q; col = query = ln
    { f32x16 z = {0.f}; oacc[0] = z; oacc[1] = z; }
    float lsum = 0.f;

    // prologue: DMA first 32-key tile into buffer 0
    GLOAD_LDS16(ksrc + (size_t)ks0 * DK_, &Ks[0][w * 512]);
    GLOAD_LDS16(vsrc + ks0, &Vs[0][w * 512]);

    int p = 0;
    for (int ks = ks0; ks < ks1; ks += 32, p ^= 1) {
        __syncthreads();   // drains this wave's DMA; all waves done with buf p^1
        if (ks + 32 < ks1) {
            GLOAD_LDS16(ksrc + (size_t)(ks + 32) * DK_, &Ks[p ^ 1][w * 512]);
            GLOAD_LDS16(vsrc + (ks + 32), &Vs[p ^ 1][w * 512]);
        }
        const unsigned short* KsT = &Ks[p][0];
        const unsigned short* VsT = &Vs[p][0];

        // S^T (32 keys x 32 q): A = K rows (m = key = ln)
        f32x16 st = {0.f};
        __builtin_amdgcn_s_setprio(1);
#pragma unroll
        for (int s = 0; s < 4; s++) {
            bf16x8 kf = *(const bf16x8*)&KsT[ln * 64 + ((2 * s + hf) ^ swz) * 8];
            st = __builtin_amdgcn_mfma_f32_32x32x16_bf16(kf, qf[s], st, 0, 0, 0);
        }
        __builtin_amdgcn_s_setprio(0);
        // softmax (no max needed: scores bounded, pre-scaled by log2e)
        float e[16];
#pragma unroll
        for (int r = 0; r < 16; r++) e[r] = EXP2F(st[r]);
        lsum += ((e[0] + e[1]) + (e[2] + e[3])) + ((e[4] + e[5]) + (e[6] + e[7]))
              + ((e[8] + e[9]) + (e[10] + e[11])) + ((e[12] + e[13]) + (e[14] + e[15]));
        unsigned int g[8];
#pragma unroll
        for (int gi = 0; gi < 8; gi++) g[gi] = pkbf(e[2 * gi], e[2 * gi + 1]);
        pl32swap(g[0], g[2]); pl32swap(g[1], g[3]);   // b0 = keys 0-15
        pl32swap(g[4], g[6]); pl32swap(g[5], g[7]);   // b1 = keys 16-31
        bf16x8 b0, b1;
        { uint4v t = {g[0], g[1], g[2], g[3]}; __builtin_memcpy(&b0, &t, 16); }
        { uint4v t = {g[4], g[5], g[6], g[7]}; __builtin_memcpy(&b1, &t, 16); }
        // O^T += V^T . P^T : A = V^T rows (m = d = dt*32+ln), 32-key k
        __builtin_amdgcn_s_setprio(1);
#pragma unroll
        for (int dt = 0; dt < 2; dt++) {
            int r = dt * 32 + ln;
            bf16x8 vf0 = *(const bf16x8*)&VsT[r * 32 + ((hf) ^ (ln & 3)) * 8];
            bf16x8 vf1 = *(const bf16x8*)&VsT[r * 32 + ((2 + hf) ^ (ln & 3)) * 8];
            oacc[dt] = __builtin_amdgcn_mfma_f32_32x32x16_bf16(vf0, b0, oacc[dt], 0, 0, 0);
            oacc[dt] = __builtin_amdgcn_mfma_f32_32x32x16_bf16(vf1, b1, oacc[dt], 0, 0, 0);
        }
        __builtin_amdgcn_s_setprio(0);
    }

    // per-split denominator (both lane-halves combined)
    float ltot = lsum + __shfl_xor(lsum, 32, 64);
    if (hf == 0)
        lpart[(size_t)sp * (16 * S_LEN) + (size_t)bh * S_LEN + q0 + ln] = ltot;

    int bb = bh >> 3, hh = bh & 7;
    int token = bb * S_LEN + q0 + ln;
    float* op = Opart + (size_t)sp * NTOK * DM_;
#pragma unroll
    for (int dt = 0; dt < 2; dt++)
#pragma unroll
        for (int gi = 0; gi < 8; gi++) {
            int d = dt * 32 + 2 * (gi & 1) + 8 * (gi >> 1) + 4 * hf;
            float2 o; o.x = oacc[dt][2 * gi]; o.y = oacc[dt][2 * gi + 1];
            *(float2*)&op[(size_t)token * DM_ + hh * DK_ + d] = o;
        }
}

// ---------- merge NSP key-split partials -> normalized bf16 Ao ----------
template <int NSP>
__global__ __launch_bounds__(256) void merge_split(const float* __restrict__ Opart,
                                                   const float* __restrict__ lpart,
                                                   unsigned short* __restrict__ Ao) {
    size_t e = ((size_t)blockIdx.x * 256 + threadIdx.x) * 4;   // 4 f32 elems, same head
    int token = (int)(e >> 9);
    int c = (int)(e & 511);
    int hh = c >> 6;
    int bb = token >> 12, s = token & 4095;
    size_t li = (size_t)(bb * NHEAD + hh) * S_LEN + s;
    float ltot = 0.f;
#pragma unroll
    for (int j = 0; j < NSP; j++) ltot += lpart[(size_t)j * (16 * S_LEN) + li];
    float inv = 1.0f / ltot;
    float4 a = *(const float4*)&Opart[e];
#pragma unroll
    for (int j = 1; j < NSP; j++) {
        float4 b = *(const float4*)&Opart[(size_t)j * NTOK * DM_ + e];
        a.x += b.x; a.y += b.y; a.z += b.z; a.w += b.w;
    }
    uint2 o;
    o.x = pkbf(a.x * inv, a.y * inv);
    o.y = pkbf(a.z * inv, a.w * inv);
    *(uint2*)&Ao[e] = o;
}

// ---------- output GEMM: out = Ao(bf16)@Wo + bo, fp32 out ----------
__global__ __launch_bounds__(256) void out_gemm(const unsigned short* __restrict__ A,
                                                const unsigned short* __restrict__ Wt,
                                                const float* __restrict__ bias, float* __restrict__ out) {
    __shared__ unsigned short As[128 * 40];
    __shared__ unsigned short Bs[128 * 40];
    int tid = threadIdx.x;
    int n0 = blockIdx.x * 128, m0 = blockIdx.y * 128;
    int w = tid >> 6, lane = tid & 63;
    int ln = lane & 15, qd = lane >> 4;
    int mb = (w >> 1) * 64, nb = (w & 1) * 64;

    f32x4 acc[4][4];
#pragma unroll
    for (int i = 0; i < 4; i++)
#pragma unroll
        for (int j = 0; j < 4; j++) { f32x4 z = {0.f, 0.f, 0.f, 0.f}; acc[i][j] = z; }

    for (int kk = 0; kk < DM_; kk += 32) {
        __syncthreads();
#pragma unroll
        for (int i = 0; i < 2; i++) {
            int idx = i * 256 + tid;
            int row = idx >> 2, k8 = (idx & 3) * 8;
            uint4 va = *(const uint4*)&A[(size_t)(m0 + row) * DM_ + kk + k8];
            *(uint4*)&As[row * 40 + k8] = va;
            uint4 vb = *(const uint4*)&Wt[(size_t)(n0 + row) * DM_ + kk + k8];
            *(uint4*)&Bs[row * 40 + k8] = vb;
        }
        __syncthreads();
        bf16x8 af[4], bf[4];
#pragma unroll
        for (int mt = 0; mt < 4; mt++) af[mt] = *(const bf16x8*)&As[(mb + mt * 16 + ln) * 40 + qd * 8];
#pragma unroll
        for (int nt = 0; nt < 4; nt++) bf[nt] = *(const bf16x8*)&Bs[(nb + nt * 16 + ln) * 40 + qd * 8];
#pragma unroll
        for (int mt = 0; mt < 4; mt++)
#pragma unroll
            for (int nt = 0; nt < 4; nt++)
                acc[mt][nt] = __builtin_amdgcn_mfma_f32_16x16x32_bf16(af[mt], bf[nt], acc[mt][nt], 0, 0, 0);
    }

    float bv[4];
#pragma unroll
    for (int nt = 0; nt < 4; nt++) bv[nt] = bias[n0 + nb + nt * 16 + ln];
#pragma unroll
    for (int mt = 0; mt < 4; mt++) {
        int mrow0 = m0 + mb + mt * 16 + qd * 4;
#pragma unroll
        for (int nt = 0; nt < 4; nt++) {
            int ncol = n0 + nb + nt * 16 + ln;
#pragma unroll
            for (int r = 0; r < 4; r++)
                out[(size_t)(mrow0 + r) * DM_ + ncol] = acc[mt][nt][r] + bv[nt];
        }
    }
}

extern "C" void kernel_launch(void* const* d_in, const int* in_sizes, int n_in,
                              void* d_out, int out_size, void* d_ws, size_t ws_size,
                              hipStream_t stream) {
    const float* q  = (const float*)d_in[0];
    const float* k  = (const float*)d_in[1];
    const float* v  = (const float*)d_in[2];
    const float* Wq = (const float*)d_in[3];
    const float* bq = (const float*)d_in[4];
    const float* Wk = (const float*)d_in[5];
    const float* bk = (const float*)d_in[6];
    const float* Wv = (const float*)d_in[7];
    const float* bv = (const float*)d_in[8];
    const float* Wo = (const float*)d_in[9];
    const float* bo = (const float*)d_in[10];
    float* out = (float*)d_out;

    unsigned short* Wt  = (unsigned short*)d_ws;
    unsigned short* Qh  = Wt + (size_t)4 * DM_ * DM_;
    unsigned short* Kh  = Qh + (size_t)NTOK * DM_;
    unsigned short* VhT = Kh + (size_t)NTOK * DM_;
    unsigned short* tail = VhT + (size_t)NTOK * DM_;

    size_t head_b  = ((size_t)4 * DM_ * DM_ + (size_t)3 * NTOK * DM_) * 2;
    size_t opart_b4 = (size_t)4 * NTOK * DM_ * 4;
    size_t lpart_b4 = (size_t)4 * 16 * S_LEN * 4;
    size_t opart_b2 = (size_t)2 * NTOK * DM_ * 4;
    size_t lpart_b2 = (size_t)2 * 16 * S_LEN * 4;
    size_t ao_b     = (size_t)NTOK * DM_ * 2;
    size_t need_sp4 = head_b + opart_b4 + lpart_b4 + ao_b;
    size_t need_sp2 = head_b + opart_b2 + lpart_b2 + ao_b;
    size_t need_bf  = ((size_t)4 * DM_ * DM_ + (size_t)6 * NTOK * DM_) * 2;

    wtrans<<<dim3(8, 8, 4), 256, 0, stream>>>(Wq, Wk, Wv, Wo, Wt);
    if (ws_size >= need_sp4) {
        // tail layout: [Opart 4x f32][lpart 4x][Ao bf16]; Xbf aliases head of Opart
        float* Opart = (float*)tail;
        float* lpart = Opart + (size_t)4 * NTOK * DM_;
        unsigned short* Ao = (unsigned short*)(lpart + (size_t)4 * 16 * S_LEN);
        unsigned short* Xbf = tail;
        xcvt<<<dim3(4096, 3), 256, 0, stream>>>(q, k, v, Xbf);
        qkv_bf<<<dim3(4, 64, 3), 256, 0, stream>>>(Xbf, Wt, bq, bk, bv, Qh, Kh, VhT);
        flash_attn_kv32<<<dim3(2048), 256, 0, stream>>>(Qh, Kh, VhT, Opart, lpart);
        merge_split<4><<<dim3(4096), 256, 0, stream>>>(Opart, lpart, Ao);
        out_gemm<<<dim3(4, 64), 256, 0, stream>>>(Ao, Wt + (size_t)3 * DM_ * DM_, bo, out);
    } else if (ws_size >= need_sp2) {
        float* Opart = (float*)tail;
        float* lpart = Opart + (size_t)2 * NTOK * DM_;
        unsigned short* Ao = (unsigned short*)(lpart + (size_t)2 * 16 * S_LEN);
        unsigned short* Xbf = tail;
        xcvt<<<dim3(4096, 3), 256, 0, stream>>>(q, k, v, Xbf);
        qkv_bf<<<dim3(4, 64, 3), 256, 0, stream>>>(Xbf, Wt, bq, bk, bv, Qh, Kh, VhT);
        flash_attn_sp<<<dim3(1024), 256, 0, stream>>>(Qh, Kh, VhT, Opart, lpart);
        merge_split<2><<<dim3(4096), 256, 0, stream>>>(Opart, lpart, Ao);
        out_gemm<<<dim3(4, 64), 256, 0, stream>>>(Ao, Wt + (size_t)3 * DM_ * DM_, bo, out);
    } else if (ws_size >= need_bf) {
        unsigned short* Xbf = tail;   // Ao aliases Xbf head (Xbf dead before flash writes Ao)
        unsigned short* Ao = tail;
        xcvt<<<dim3(4096, 3), 256, 0, stream>>>(q, k, v, Xbf);
        qkv_bf<<<dim3(4, 64, 3), 256, 0, stream>>>(Xbf, Wt, bq, bk, bv, Qh, Kh, VhT);
        flash_attn<<<dim3(512), 256, 0, stream>>>(Qh, Kh, VhT, Ao);
        out_gemm<<<dim3(4, 64), 256, 0, stream>>>(Ao, Wt + (size_t)3 * DM_ * DM_, bo, out);
    } else {
        unsigned short* Ao = tail;
        qkv_proj<<<dim3(4, 64, 3), 256, 0, stream>>>(q, k, v, Wt, bq, bk, bv, Qh, Kh, VhT);
        flash_attn<<<dim3(512), 256, 0, stream>>>(Qh, Kh, VhT, Ao);
        out_gemm<<<dim3(4, 64), 256, 0, stream>>>(Ao, Wt + (size_t)3 * DM_ * DM_, bo, out);
    }
}

// Round 5
// 249.659 us; speedup vs baseline: 1.5403x; 1.0448x over previous
//
#include <hip/hip_runtime.h>
#include <hip/hip_bf16.h>

#define NHEAD 8
#define DK_ 64
#define DM_ 512
#define S_LEN 4096
#define NTOK 8192

typedef __bf16 bf16x8 __attribute__((ext_vector_type(8)));
typedef float f32x4 __attribute__((ext_vector_type(4)));
typedef float f32x16 __attribute__((ext_vector_type(16)));
typedef unsigned int uint4v __attribute__((ext_vector_type(4)));

__device__ __forceinline__ unsigned short f2bf(float f) {
    union { float f; unsigned u; } x; x.f = f;
    unsigned u = x.u;
    u += 0x7FFFu + ((u >> 16) & 1u);   // round-to-nearest-even (inputs finite)
    return (unsigned short)(u >> 16);
}

// packed f32x2 -> bf16x2 (gfx950 HW op when available; RNE either way)
#if __has_builtin(__builtin_amdgcn_cvt_pk_bf16_f32)
__device__ __forceinline__ unsigned int pkbf(float a, float b) {
    auto r = __builtin_amdgcn_cvt_pk_bf16_f32(a, b);
    unsigned int u; __builtin_memcpy(&u, &r, 4); return u;
}
#else
__device__ __forceinline__ unsigned int pkbf(float a, float b) {
    return (unsigned)f2bf(a) | ((unsigned)f2bf(b) << 16);
}
#endif

#if __has_builtin(__builtin_amdgcn_exp2f)
#define EXP2F(x) __builtin_amdgcn_exp2f(x)
#else
#define EXP2F(x) exp2f(x)
#endif

// lane-half <-> reg exchange: new_a = {a_lo, b_lo}, new_b = {a_hi, b_hi}
#if __has_builtin(__builtin_amdgcn_permlane32_swap)
__device__ __forceinline__ void pl32swap(unsigned int& a, unsigned int& b) {
    auto r = __builtin_amdgcn_permlane32_swap(a, b, false, false);
    a = r[0]; b = r[1];
}
#else
__device__ __forceinline__ void pl32swap(unsigned int& a, unsigned int& b) {
    int lane = threadIdx.x & 63;
    unsigned int ax = __shfl_xor((int)a, 32, 64);
    unsigned int bx = __shfl_xor((int)b, 32, 64);
    unsigned int na = (lane < 32) ? a : bx;
    unsigned int nb = (lane < 32) ? ax : b;
    a = na; b = nb;
}
#endif

// async global->LDS, 16B per lane; LDS dest = wave-uniform base + lane*16
#define GLOAD_LDS16(gptr, ldsbase) \
    __builtin_amdgcn_global_load_lds((const __attribute__((address_space(1))) unsigned int*)(gptr), \
                                     (__attribute__((address_space(3))) unsigned int*)(ldsbase), 16, 0, 0)

// ---------- prep: fused xcvt (z<3) + wtrans (z==3) -> one launch ----------
__global__ __launch_bounds__(256) void prep(const float* __restrict__ q, const float* __restrict__ k,
                                            const float* __restrict__ v,
                                            const float* __restrict__ Wq, const float* __restrict__ Wk,
                                            const float* __restrict__ Wv, const float* __restrict__ Wo,
                                            unsigned short* __restrict__ Xbf, unsigned short* __restrict__ Wt) {
    __shared__ float t[64][65];
    int z = blockIdx.y;
    int tid = threadIdx.x;
    if (z < 3) {
        const float* X = (z == 0) ? q : (z == 1) ? k : v;
        size_t off = (size_t)blockIdx.x * 1024 + tid * 4;
        float4 val = *(const float4*)&X[off];
        uint2 o; o.x = pkbf(val.x, val.y); o.y = pkbf(val.z, val.w);
        *(uint2*)&Xbf[(size_t)z * NTOK * DM_ + off] = o;
        return;
    }
    int bi = blockIdx.x;
    if (bi >= 256) return;
    int zz = bi >> 6;
    int bn = (bi & 7) * 64, bk = ((bi >> 3) & 7) * 64;
    const float* W = (zz == 0) ? Wq : (zz == 1) ? Wk : (zz == 2) ? Wv : Wo;
    unsigned short* out = Wt + (size_t)zz * DM_ * DM_;
    int r0 = tid >> 4, c4 = (tid & 15) * 4;
#pragma unroll
    for (int i = 0; i < 4; i++) {
        int r = r0 + i * 16;
        float4 vv = *(const float4*)&W[(size_t)(bk + r) * DM_ + bn + c4];
        t[r][c4] = vv.x; t[r][c4 + 1] = vv.y; t[r][c4 + 2] = vv.z; t[r][c4 + 3] = vv.w;
    }
    __syncthreads();
    int n0 = tid >> 4, k4 = (tid & 15) * 4;
#pragma unroll
    for (int i = 0; i < 4; i++) {
        int n = n0 + i * 16;
        ushort4 o;
        o.x = f2bf(t[k4 + 0][n]); o.y = f2bf(t[k4 + 1][n]);
        o.z = f2bf(t[k4 + 2][n]); o.w = f2bf(t[k4 + 3][n]);
        *(ushort4*)&out[(size_t)(bn + n) * DM_ + bk + k4] = o;
    }
}

// ---------- standalone wtrans (smallest-ws fallback path) ----------
__global__ __launch_bounds__(256) void wtrans(const float* __restrict__ Wq, const float* __restrict__ Wk,
                                              const float* __restrict__ Wv, const float* __restrict__ Wo,
                                              unsigned short* __restrict__ Wt) {
    int z = blockIdx.z;
    const float* W = (z == 0) ? Wq : (z == 1) ? Wk : (z == 2) ? Wv : Wo;
    unsigned short* out = Wt + (size_t)z * DM_ * DM_;
    __shared__ float t[64][65];
    int bn = blockIdx.x * 64, bk = blockIdx.y * 64;
    int tid = threadIdx.x;
    int r0 = tid >> 4, c4 = (tid & 15) * 4;
#pragma unroll
    for (int i = 0; i < 4; i++) {
        int r = r0 + i * 16;
        float4 v = *(const float4*)&W[(size_t)(bk + r) * DM_ + bn + c4];
        t[r][c4] = v.x; t[r][c4 + 1] = v.y; t[r][c4 + 2] = v.z; t[r][c4 + 3] = v.w;
    }
    __syncthreads();
    int n0 = tid >> 4, k4 = (tid & 15) * 4;
#pragma unroll
    for (int i = 0; i < 4; i++) {
        int n = n0 + i * 16;
        ushort4 o;
        o.x = f2bf(t[k4 + 0][n]); o.y = f2bf(t[k4 + 1][n]);
        o.z = f2bf(t[k4 + 2][n]); o.w = f2bf(t[k4 + 3][n]);
        *(ushort4*)&out[(size_t)(bn + n) * DM_ + bk + k4] = o;
    }
}

// shared epilogue for projection GEMMs
__device__ __forceinline__ void proj_epilogue(int z, f32x4 (&acc)[4][4], const float* bias,
                                              unsigned short* out, float scale,
                                              int m0, int n0, int mb, int nb, int ln, int qd) {
    float bvv[4];
#pragma unroll
    for (int nt = 0; nt < 4; nt++) bvv[nt] = bias[n0 + nb + nt * 16 + ln];
#pragma unroll
    for (int mt = 0; mt < 4; mt++) {
        int mrow0 = m0 + mb + mt * 16 + qd * 4;
        int b = mrow0 >> 12, s = mrow0 & 4095;
#pragma unroll
        for (int nt = 0; nt < 4; nt++) {
            int ncol = n0 + nb + nt * 16 + ln;
            int h = ncol >> 6, d = ncol & 63;
            if (z == 2) {
                uint2 o;
                o.x = pkbf((acc[mt][nt][0] + bvv[nt]) * scale, (acc[mt][nt][1] + bvv[nt]) * scale);
                o.y = pkbf((acc[mt][nt][2] + bvv[nt]) * scale, (acc[mt][nt][3] + bvv[nt]) * scale);
                *(uint2*)&out[((size_t)(b * NHEAD + h) * DK_ + d) * S_LEN + s] = o;
            } else {
#pragma unroll
                for (int r = 0; r < 4; r++)
                    out[((size_t)(b * NHEAD + h) * S_LEN + (s + r)) * DK_ + d] =
                        f2bf((acc[mt][nt][r] + bvv[nt]) * scale);
            }
        }
    }
}

// ---------- fused QKV projection from pre-converted bf16 X ----------
__global__ __launch_bounds__(256, 3) void qkv_bf(const unsigned short* __restrict__ Xbf,
                                                 const unsigned short* __restrict__ Wt,
                                                 const float* __restrict__ bq, const float* __restrict__ bk,
                                                 const float* __restrict__ bv,
                                                 unsigned short* __restrict__ Qh, unsigned short* __restrict__ Kh,
                                                 unsigned short* __restrict__ VhT) {
    int z = blockIdx.z;
    const unsigned short* X = Xbf + (size_t)z * NTOK * DM_;
    const unsigned short* W = Wt + (size_t)z * DM_ * DM_;
    const float* bias = (z == 0) ? bq : (z == 1) ? bk : bv;
    unsigned short* out = (z == 0) ? Qh : (z == 1) ? Kh : VhT;
    float scale = (z == 0) ? 0.125f * 1.44269504f : 1.0f;

    __shared__ unsigned short As[128 * 40];
    __shared__ unsigned short Bs[128 * 40];
    int tid = threadIdx.x;
    int n0 = blockIdx.x * 128, m0 = blockIdx.y * 128;
    int w = tid >> 6, lane = tid & 63;
    int ln = lane & 15, qd = lane >> 4;
    int mb = (w >> 1) * 64, nb = (w & 1) * 64;

    f32x4 acc[4][4];
#pragma unroll
    for (int i = 0; i < 4; i++)
#pragma unroll
        for (int j = 0; j < 4; j++) { f32x4 zz = {0.f, 0.f, 0.f, 0.f}; acc[i][j] = zz; }

    for (int kk = 0; kk < DM_; kk += 32) {
        __syncthreads();
#pragma unroll
        for (int i = 0; i < 2; i++) {
            int idx = i * 256 + tid;
            int row = idx >> 2, k8 = (idx & 3) * 8;
            uint4 va = *(const uint4*)&X[(size_t)(m0 + row) * DM_ + kk + k8];
            *(uint4*)&As[row * 40 + k8] = va;
            uint4 vb = *(const uint4*)&W[(size_t)(n0 + row) * DM_ + kk + k8];
            *(uint4*)&Bs[row * 40 + k8] = vb;
        }
        __syncthreads();
        bf16x8 af[4], bf[4];
#pragma unroll
        for (int mt = 0; mt < 4; mt++) af[mt] = *(const bf16x8*)&As[(mb + mt * 16 + ln) * 40 + qd * 8];
#pragma unroll
        for (int nt = 0; nt < 4; nt++) bf[nt] = *(const bf16x8*)&Bs[(nb + nt * 16 + ln) * 40 + qd * 8];
#pragma unroll
        for (int mt = 0; mt < 4; mt++)
#pragma unroll
            for (int nt = 0; nt < 4; nt++)
                acc[mt][nt] = __builtin_amdgcn_mfma_f32_16x16x32_bf16(af[mt], bf[nt], acc[mt][nt], 0, 0, 0);
    }
    proj_epilogue(z, acc, bias, out, scale, m0, n0, mb, nb, ln, qd);
}

// ---------- fallback fused QKV projection from fp32 X (small ws) ----------
__global__ __launch_bounds__(256, 3) void qkv_proj(const float* __restrict__ xq, const float* __restrict__ xk,
                                                   const float* __restrict__ xv, const unsigned short* __restrict__ Wt,
                                                   const float* __restrict__ bq, const float* __restrict__ bk,
                                                   const float* __restrict__ bv,
                                                   unsigned short* __restrict__ Qh, unsigned short* __restrict__ Kh,
                                                   unsigned short* __restrict__ VhT) {
    int z = blockIdx.z;
    const float* X = (z == 0) ? xq : (z == 1) ? xk : xv;
    const unsigned short* W = Wt + (size_t)z * DM_ * DM_;
    const float* bias = (z == 0) ? bq : (z == 1) ? bk : bv;
    unsigned short* out = (z == 0) ? Qh : (z == 1) ? Kh : VhT;
    float scale = (z == 0) ? 0.125f * 1.44269504f : 1.0f;

    __shared__ unsigned short As[128 * 40];
    __shared__ unsigned short Bs[128 * 40];
    int tid = threadIdx.x;
    int n0 = blockIdx.x * 128, m0 = blockIdx.y * 128;
    int w = tid >> 6, lane = tid & 63;
    int ln = lane & 15, qd = lane >> 4;
    int mb = (w >> 1) * 64, nb = (w & 1) * 64;

    f32x4 acc[4][4];
#pragma unroll
    for (int i = 0; i < 4; i++)
#pragma unroll
        for (int j = 0; j < 4; j++) { f32x4 zz = {0.f, 0.f, 0.f, 0.f}; acc[i][j] = zz; }

    for (int kk = 0; kk < DM_; kk += 32) {
        __syncthreads();
#pragma unroll
        for (int i = 0; i < 4; i++) {
            int idx = i * 256 + tid;
            int row = idx >> 3, k4 = (idx & 7) * 4;
            float4 v = *(const float4*)&X[(size_t)(m0 + row) * DM_ + kk + k4];
            uint2 o; o.x = pkbf(v.x, v.y); o.y = pkbf(v.z, v.w);
            *(uint2*)&As[row * 40 + k4] = o;
        }
#pragma unroll
        for (int i = 0; i < 2; i++) {
            int idx = i * 256 + tid;
            int row = idx >> 2, k8 = (idx & 3) * 8;
            uint4 v = *(const uint4*)&W[(size_t)(n0 + row) * DM_ + kk + k8];
            *(uint4*)&Bs[row * 40 + k8] = v;
        }
        __syncthreads();
        bf16x8 af[4], bf[4];
#pragma unroll
        for (int mt = 0; mt < 4; mt++) af[mt] = *(const bf16x8*)&As[(mb + mt * 16 + ln) * 40 + qd * 8];
#pragma unroll
        for (int nt = 0; nt < 4; nt++) bf[nt] = *(const bf16x8*)&Bs[(nb + nt * 16 + ln) * 40 + qd * 8];
#pragma unroll
        for (int mt = 0; mt < 4; mt++)
#pragma unroll
            for (int nt = 0; nt < 4; nt++)
                acc[mt][nt] = __builtin_amdgcn_mfma_f32_16x16x32_bf16(af[mt], bf[nt], acc[mt][nt], 0, 0, 0);
    }
    proj_epilogue(z, acc, bias, out, scale, m0, n0, mb, nb, ln, qd);
}

// ---------- flash attention (legacy single-pass, small-ws fallback) ----------
__global__ __launch_bounds__(256, 2) void flash_attn(const unsigned short* __restrict__ Qh,
                                                     const unsigned short* __restrict__ Kh,
                                                     const unsigned short* __restrict__ VhT,
                                                     unsigned short* __restrict__ Ao) {
    __shared__ unsigned short Ks[2][64 * 64];     // 16 KB
    __shared__ unsigned short Vs[2][64 * 64];     // 16 KB
    int i = blockIdx.x;
    int bh = (i & 7) + 8 * ((i >> 3) & 1);
    int qb = i >> 4;
    int tid = threadIdx.x;
    int w = tid >> 6, lane = tid & 63;
    int ln = lane & 31, hf = lane >> 5;
    int swz = ln & 7;
    int q0 = qb * 128 + w * 32;
    const unsigned short* Qp = Qh + (size_t)bh * S_LEN * DK_;
    const unsigned short* Kp = Kh + (size_t)bh * S_LEN * DK_;
    const unsigned short* Vp = VhT + (size_t)bh * DK_ * S_LEN;

    int sr = lane >> 3;
    int sc = (lane & 7) ^ sr;
    const unsigned short* ksrc = Kp + (size_t)(w * 16 + sr) * DK_ + sc * 8;
    const unsigned short* vsrc = Vp + (size_t)(w * 16 + sr) * S_LEN + sc * 8;

    bf16x8 qf[4];
#pragma unroll
    for (int s = 0; s < 4; s++)
        qf[s] = *(const bf16x8*)&Qp[(size_t)(q0 + ln) * DK_ + s * 16 + hf * 8];

    f32x16 oacc[2];
    { f32x16 z = {0.f}; oacc[0] = z; oacc[1] = z; }
    float lsum = 0.f;

    GLOAD_LDS16(ksrc, &Ks[0][w * 1024]);
    GLOAD_LDS16(ksrc + (size_t)8 * DK_, &Ks[0][w * 1024 + 512]);
    GLOAD_LDS16(vsrc, &Vs[0][w * 1024]);
    GLOAD_LDS16(vsrc + (size_t)8 * S_LEN, &Vs[0][w * 1024 + 512]);

    int p = 0;
    for (int ks = 0; ks < S_LEN; ks += 64, p ^= 1) {
        __syncthreads();
        if (ks + 64 < S_LEN) {
            const unsigned short* kn = ksrc + (size_t)(ks + 64) * DK_;
            const unsigned short* vn = vsrc + (ks + 64);
            GLOAD_LDS16(kn, &Ks[p ^ 1][w * 1024]);
            GLOAD_LDS16(kn + (size_t)8 * DK_, &Ks[p ^ 1][w * 1024 + 512]);
            GLOAD_LDS16(vn, &Vs[p ^ 1][w * 1024]);
            GLOAD_LDS16(vn + (size_t)8 * S_LEN, &Vs[p ^ 1][w * 1024 + 512]);
        }
        const unsigned short* KsT = &Ks[p][0];
        const unsigned short* VsT = &Vs[p][0];

#pragma unroll
        for (int kb = 0; kb < 2; kb++) {
            f32x16 st = {0.f};
#pragma unroll
            for (int s = 0; s < 4; s++) {
                bf16x8 kf = *(const bf16x8*)&KsT[(kb * 32 + ln) * 64 + ((2 * s + hf) ^ swz) * 8];
                st = __builtin_amdgcn_mfma_f32_32x32x16_bf16(kf, qf[s], st, 0, 0, 0);
            }
            float e[16];
#pragma unroll
            for (int r = 0; r < 16; r++) e[r] = EXP2F(st[r]);
            lsum += ((e[0] + e[1]) + (e[2] + e[3])) + ((e[4] + e[5]) + (e[6] + e[7]))
                  + ((e[8] + e[9]) + (e[10] + e[11])) + ((e[12] + e[13]) + (e[14] + e[15]));
            unsigned int g[8];
#pragma unroll
            for (int gi = 0; gi < 8; gi++) g[gi] = pkbf(e[2 * gi], e[2 * gi + 1]);
            pl32swap(g[0], g[2]); pl32swap(g[1], g[3]);
            pl32swap(g[4], g[6]); pl32swap(g[5], g[7]);
            bf16x8 b0, b1;
            { uint4v t = {g[0], g[1], g[2], g[3]}; __builtin_memcpy(&b0, &t, 16); }
            { uint4v t = {g[4], g[5], g[6], g[7]}; __builtin_memcpy(&b1, &t, 16); }
#pragma unroll
            for (int dt = 0; dt < 2; dt++) {
                int s0 = kb * 2;
                bf16x8 vf0 = *(const bf16x8*)&VsT[(dt * 32 + ln) * 64 + ((2 * s0 + hf) ^ swz) * 8];
                bf16x8 vf1 = *(const bf16x8*)&VsT[(dt * 32 + ln) * 64 + ((2 * s0 + 2 + hf) ^ swz) * 8];
                oacc[dt] = __builtin_amdgcn_mfma_f32_32x32x16_bf16(vf0, b0, oacc[dt], 0, 0, 0);
                oacc[dt] = __builtin_amdgcn_mfma_f32_32x32x16_bf16(vf1, b1, oacc[dt], 0, 0, 0);
            }
        }
    }

    float ltot = lsum + __shfl_xor(lsum, 32, 64);
    float inv = 1.0f / ltot;

    int bb = bh >> 3, hh = bh & 7;
    int token = bb * S_LEN + q0 + ln;
#pragma unroll
    for (int dt = 0; dt < 2; dt++)
#pragma unroll
        for (int gi = 0; gi < 8; gi++) {
            int d = dt * 32 + 2 * (gi & 1) + 8 * (gi >> 1) + 4 * hf;
            unsigned int o = pkbf(oacc[dt][2 * gi] * inv, oacc[dt][2 * gi + 1] * inv);
            *(unsigned int*)&Ao[(size_t)token * DM_ + hh * DK_ + d] = o;
        }
}

// ---------- split-K flash v5: sp skeleton + 2-deep kb pipeline + zero-C ----------
// r4 post-mortem: TLP lever exhausted (every occupancy gain bought a bigger
// mechanical regression). v5 returns to the proven sp shape (NSP=2, KVBLK=64,
// 32q/wave, 4 blocks/CU, conflicts ~4.2M) and attacks per-wave ILP + VALU
// issue count: (1) QK0 and QK1 issued back-to-back -> 8 independent MFMAs in
// flight while exp2(st0) runs on the trans pipe; (2) first MFMA of each S^T
// uses a persistent zero vector as C (kills 16 v_mov inits per 32-key block);
// (3) setprio around MFMA clusters. Peak live VGPR ~116 < 128 cap (no spill).
__global__ __launch_bounds__(256, 4) void flash_attn_v5(const unsigned short* __restrict__ Qh,
                                                        const unsigned short* __restrict__ Kh,
                                                        const unsigned short* __restrict__ VhT,
                                                        float* __restrict__ Opart,
                                                        float* __restrict__ lpart) {
    __shared__ unsigned short Ks[2][64 * 64];     // 16 KB
    __shared__ unsigned short Vs[2][64 * 64];     // 16 KB
    int i = blockIdx.x;
    int bh = (i & 7) + 8 * ((i >> 3) & 1);
    int qb = (i >> 4) & 31;
    int sp = i >> 9;
    int ks0 = sp * (S_LEN / 2);
    int ks1 = ks0 + (S_LEN / 2);
    int tid = threadIdx.x;
    int w = tid >> 6, lane = tid & 63;
    int ln = lane & 31, hf = lane >> 5;
    int swz = ln & 7;
    int q0 = qb * 128 + w * 32;
    const unsigned short* Qp = Qh + (size_t)bh * S_LEN * DK_;
    const unsigned short* Kp = Kh + (size_t)bh * S_LEN * DK_;
    const unsigned short* Vp = VhT + (size_t)bh * DK_ * S_LEN;

    int sr = lane >> 3;
    int sc = (lane & 7) ^ sr;
    const unsigned short* ksrc = Kp + (size_t)(w * 16 + sr) * DK_ + sc * 8;
    const unsigned short* vsrc = Vp + (size_t)(w * 16 + sr) * S_LEN + sc * 8;

    bf16x8 qf[4];
#pragma unroll
    for (int s = 0; s < 4; s++)
        qf[s] = *(const bf16x8*)&Qp[(size_t)(q0 + ln) * DK_ + s * 16 + hf * 8];

    f32x16 zz16 = {0.f};          // persistent zero C-operand
    f32x16 oacc[2];
    { f32x16 z = {0.f}; oacc[0] = z; oacc[1] = z; }
    float lsum = 0.f;

    GLOAD_LDS16(ksrc + (size_t)ks0 * DK_, &Ks[0][w * 1024]);
    GLOAD_LDS16(ksrc + (size_t)(ks0 + 8) * DK_, &Ks[0][w * 1024 + 512]);
    GLOAD_LDS16(vsrc + ks0, &Vs[0][w * 1024]);
    GLOAD_LDS16(vsrc + ks0 + (size_t)8 * S_LEN, &Vs[0][w * 1024 + 512]);

    int p = 0;
    for (int ks = ks0; ks < ks1; ks += 64, p ^= 1) {
        __syncthreads();   // drains DMA for buf p; all waves done reading buf p^1
        if (ks + 64 < ks1) {
            const unsigned short* kn = ksrc + (size_t)(ks + 64) * DK_;
            const unsigned short* vn = vsrc + (ks + 64);
            GLOAD_LDS16(kn, &Ks[p ^ 1][w * 1024]);
            GLOAD_LDS16(kn + (size_t)8 * DK_, &Ks[p ^ 1][w * 1024 + 512]);
            GLOAD_LDS16(vn, &Vs[p ^ 1][w * 1024]);
            GLOAD_LDS16(vn + (size_t)8 * S_LEN, &Vs[p ^ 1][w * 1024 + 512]);
        }
        const unsigned short* KsT = &Ks[p][0];
        const unsigned short* VsT = &Vs[p][0];

        // ---- QK^T for BOTH 32-key halves back-to-back (8 independent MFMAs) ----
        f32x16 st0, st1;
        __builtin_amdgcn_s_setprio(1);
        {
            bf16x8 kf = *(const bf16x8*)&KsT[ln * 64 + ((hf) ^ swz) * 8];
            st0 = __builtin_amdgcn_mfma_f32_32x32x16_bf16(kf, qf[0], zz16, 0, 0, 0);
        }
#pragma unroll
        for (int s = 1; s < 4; s++) {
            bf16x8 kf = *(const bf16x8*)&KsT[ln * 64 + ((2 * s + hf) ^ swz) * 8];
            st0 = __builtin_amdgcn_mfma_f32_32x32x16_bf16(kf, qf[s], st0, 0, 0, 0);
        }
        {
            bf16x8 kf = *(const bf16x8*)&KsT[(32 + ln) * 64 + ((hf) ^ swz) * 8];
            st1 = __builtin_amdgcn_mfma_f32_32x32x16_bf16(kf, qf[0], zz16, 0, 0, 0);
        }
#pragma unroll
        for (int s = 1; s < 4; s++) {
            bf16x8 kf = *(const bf16x8*)&KsT[(32 + ln) * 64 + ((2 * s + hf) ^ swz) * 8];
            st1 = __builtin_amdgcn_mfma_f32_32x32x16_bf16(kf, qf[s], st1, 0, 0, 0);
        }
        __builtin_amdgcn_s_setprio(0);

        // ---- SM0: exp2 overlaps QK1's in-flight MFMAs ----
        {
            float e[16];
#pragma unroll
            for (int r = 0; r < 16; r++) e[r] = EXP2F(st0[r]);
            lsum += ((e[0] + e[1]) + (e[2] + e[3])) + ((e[4] + e[5]) + (e[6] + e[7]))
                  + ((e[8] + e[9]) + (e[10] + e[11])) + ((e[12] + e[13]) + (e[14] + e[15]));
            unsigned int g[8];
#pragma unroll
            for (int gi = 0; gi < 8; gi++) g[gi] = pkbf(e[2 * gi], e[2 * gi + 1]);
            pl32swap(g[0], g[2]); pl32swap(g[1], g[3]);
            pl32swap(g[4], g[6]); pl32swap(g[5], g[7]);
            bf16x8 b0, b1;
            { uint4v t = {g[0], g[1], g[2], g[3]}; __builtin_memcpy(&b0, &t, 16); }
            { uint4v t = {g[4], g[5], g[6], g[7]}; __builtin_memcpy(&b1, &t, 16); }
            // PV0 (chunks 0..3 of V rows)
            __builtin_amdgcn_s_setprio(1);
#pragma unroll
            for (int dt = 0; dt < 2; dt++) {
                bf16x8 vf0 = *(const bf16x8*)&VsT[(dt * 32 + ln) * 64 + ((hf) ^ swz) * 8];
                bf16x8 vf1 = *(const bf16x8*)&VsT[(dt * 32 + ln) * 64 + ((2 + hf) ^ swz) * 8];
                oacc[dt] = __builtin_amdgcn_mfma_f32_32x32x16_bf16(vf0, b0, oacc[dt], 0, 0, 0);
                oacc[dt] = __builtin_amdgcn_mfma_f32_32x32x16_bf16(vf1, b1, oacc[dt], 0, 0, 0);
            }
            __builtin_amdgcn_s_setprio(0);
        }
        // ---- SM1 + PV1 ----
        {
            float e[16];
#pragma unroll
            for (int r = 0; r < 16; r++) e[r] = EXP2F(st1[r]);
            lsum += ((e[0] + e[1]) + (e[2] + e[3])) + ((e[4] + e[5]) + (e[6] + e[7]))
                  + ((e[8] + e[9]) + (e[10] + e[11])) + ((e[12] + e[13]) + (e[14] + e[15]));
            unsigned int g[8];
#pragma unroll
            for (int gi = 0; gi < 8; gi++) g[gi] = pkbf(e[2 * gi], e[2 * gi + 1]);
            pl32swap(g[0], g[2]); pl32swap(g[1], g[3]);
            pl32swap(g[4], g[6]); pl32swap(g[5], g[7]);
            bf16x8 b0, b1;
            { uint4v t = {g[0], g[1], g[2], g[3]}; __builtin_memcpy(&b0, &t, 16); }
            { uint4v t = {g[4], g[5], g[6], g[7]}; __builtin_memcpy(&b1, &t, 16); }
            // PV1 (chunks 4..7 of V rows)
            __builtin_amdgcn_s_setprio(1);
#pragma unroll
            for (int dt = 0; dt < 2; dt++) {
                bf16x8 vf0 = *(const bf16x8*)&VsT[(dt * 32 + ln) * 64 + ((4 + hf) ^ swz) * 8];
                bf16x8 vf1 = *(const bf16x8*)&VsT[(dt * 32 + ln) * 64 + ((6 + hf) ^ swz) * 8];
                oacc[dt] = __builtin_amdgcn_mfma_f32_32x32x16_bf16(vf0, b0, oacc[dt], 0, 0, 0);
                oacc[dt] = __builtin_amdgcn_mfma_f32_32x32x16_bf16(vf1, b1, oacc[dt], 0, 0, 0);
            }
            __builtin_amdgcn_s_setprio(0);
        }
    }

    float ltot = lsum + __shfl_xor(lsum, 32, 64);
    if (hf == 0)
        lpart[(size_t)sp * (16 * S_LEN) + (size_t)bh * S_LEN + q0 + ln] = ltot;

    int bb = bh >> 3, hh = bh & 7;
    int token = bb * S_LEN + q0 + ln;
    float* op = Opart + (size_t)sp * NTOK * DM_;
#pragma unroll
    for (int dt = 0; dt < 2; dt++)
#pragma unroll
        for (int gi = 0; gi < 8; gi++) {
            int d = dt * 32 + 2 * (gi & 1) + 8 * (gi >> 1) + 4 * hf;
            float2 o; o.x = oacc[dt][2 * gi]; o.y = oacc[dt][2 * gi + 1];
            *(float2*)&op[(size_t)token * DM_ + hh * DK_ + d] = o;
        }
}

// ---------- merge NSP key-split partials -> normalized bf16 Ao ----------
template <int NSP>
__global__ __launch_bounds__(256) void merge_split(const float* __restrict__ Opart,
                                                   const float* __restrict__ lpart,
                                                   unsigned short* __restrict__ Ao) {
    size_t e = ((size_t)blockIdx.x * 256 + threadIdx.x) * 4;   // 4 f32 elems, same head
    int token = (int)(e >> 9);
    int c = (int)(e & 511);
    int hh = c >> 6;
    int bb = token >> 12, s = token & 4095;
    size_t li = (size_t)(bb * NHEAD + hh) * S_LEN + s;
    float ltot = 0.f;
#pragma unroll
    for (int j = 0; j < NSP; j++) ltot += lpart[(size_t)j * (16 * S_LEN) + li];
    float inv = 1.0f / ltot;
    float4 a = *(const float4*)&Opart[e];
#pragma unroll
    for (int j = 1; j < NSP; j++) {
        float4 b = *(const float4*)&Opart[(size_t)j * NTOK * DM_ + e];
        a.x += b.x; a.y += b.y; a.z += b.z; a.w += b.w;
    }
    uint2 o;
    o.x = pkbf(a.x * inv, a.y * inv);
    o.y = pkbf(a.z * inv, a.w * inv);
    *(uint2*)&Ao[e] = o;
}

// ---------- output GEMM: out = Ao(bf16)@Wo + bo, fp32 out ----------
__global__ __launch_bounds__(256) void out_gemm(const unsigned short* __restrict__ A,
                                                const unsigned short* __restrict__ Wt,
                                                const float* __restrict__ bias, float* __restrict__ out) {
    __shared__ unsigned short As[128 * 40];
    __shared__ unsigned short Bs[128 * 40];
    int tid = threadIdx.x;
    int n0 = blockIdx.x * 128, m0 = blockIdx.y * 128;
    int w = tid >> 6, lane = tid & 63;
    int ln = lane & 15, qd = lane >> 4;
    int mb = (w >> 1) * 64, nb = (w & 1) * 64;

    f32x4 acc[4][4];
#pragma unroll
    for (int i = 0; i < 4; i++)
#pragma unroll
        for (int j = 0; j < 4; j++) { f32x4 z = {0.f, 0.f, 0.f, 0.f}; acc[i][j] = z; }

    for (int kk = 0; kk < DM_; kk += 32) {
        __syncthreads();
#pragma unroll
        for (int i = 0; i < 2; i++) {
            int idx = i * 256 + tid;
            int row = idx >> 2, k8 = (idx & 3) * 8;
            uint4 va = *(const uint4*)&A[(size_t)(m0 + row) * DM_ + kk + k8];
            *(uint4*)&As[row * 40 + k8] = va;
            uint4 vb = *(const uint4*)&Wt[(size_t)(n0 + row) * DM_ + kk + k8];
            *(uint4*)&Bs[row * 40 + k8] = vb;
        }
        __syncthreads();
        bf16x8 af[4], bf[4];
#pragma unroll
        for (int mt = 0; mt < 4; mt++) af[mt] = *(const bf16x8*)&As[(mb + mt * 16 + ln) * 40 + qd * 8];
#pragma unroll
        for (int nt = 0; nt < 4; nt++) bf[nt] = *(const bf16x8*)&Bs[(nb + nt * 16 + ln) * 40 + qd * 8];
#pragma unroll
        for (int mt = 0; mt < 4; mt++)
#pragma unroll
            for (int nt = 0; nt < 4; nt++)
                acc[mt][nt] = __builtin_amdgcn_mfma_f32_16x16x32_bf16(af[mt], bf[nt], acc[mt][nt], 0, 0, 0);
    }

    float bv[4];
#pragma unroll
    for (int nt = 0; nt < 4; nt++) bv[nt] = bias[n0 + nb + nt * 16 + ln];
#pragma unroll
    for (int mt = 0; mt < 4; mt++) {
        int mrow0 = m0 + mb + mt * 16 + qd * 4;
#pragma unroll
        for (int nt = 0; nt < 4; nt++) {
            int ncol = n0 + nb + nt * 16 + ln;
#pragma unroll
            for (int r = 0; r < 4; r++)
                out[(size_t)(mrow0 + r) * DM_ + ncol] = acc[mt][nt][r] + bv[nt];
        }
    }
}

extern "C" void kernel_launch(void* const* d_in, const int* in_sizes, int n_in,
                              void* d_out, int out_size, void* d_ws, size_t ws_size,
                              hipStream_t stream) {
    const float* q  = (const float*)d_in[0];
    const float* k  = (const float*)d_in[1];
    const float* v  = (const float*)d_in[2];
    const float* Wq = (const float*)d_in[3];
    const float* bq = (const float*)d_in[4];
    const float* Wk = (const float*)d_in[5];
    const float* bk = (const float*)d_in[6];
    const float* Wv = (const float*)d_in[7];
    const float* bv = (const float*)d_in[8];
    const float* Wo = (const float*)d_in[9];
    const float* bo = (const float*)d_in[10];
    float* out = (float*)d_out;

    unsigned short* Wt  = (unsigned short*)d_ws;
    unsigned short* Qh  = Wt + (size_t)4 * DM_ * DM_;
    unsigned short* Kh  = Qh + (size_t)NTOK * DM_;
    unsigned short* VhT = Kh + (size_t)NTOK * DM_;
    unsigned short* tail = VhT + (size_t)NTOK * DM_;

    size_t head_b  = ((size_t)4 * DM_ * DM_ + (size_t)3 * NTOK * DM_) * 2;
    size_t opart_b2 = (size_t)2 * NTOK * DM_ * 4;
    size_t lpart_b2 = (size_t)2 * 16 * S_LEN * 4;
    size_t ao_b     = (size_t)NTOK * DM_ * 2;
    size_t need_sp2 = head_b + opart_b2 + lpart_b2 + ao_b;
    size_t need_bf  = ((size_t)4 * DM_ * DM_ + (size_t)6 * NTOK * DM_) * 2;

    if (ws_size >= need_sp2) {
        // tail layout: [Opart 2x f32][lpart 2x][Ao bf16]; Xbf aliases head of Opart
        float* Opart = (float*)tail;
        float* lpart = Opart + (size_t)2 * NTOK * DM_;
        unsigned short* Ao = (unsigned short*)(lpart + (size_t)2 * 16 * S_LEN);
        unsigned short* Xbf = tail;
        prep<<<dim3(4096, 4), 256, 0, stream>>>(q, k, v, Wq, Wk, Wv, Wo, Xbf, Wt);
        qkv_bf<<<dim3(4, 64, 3), 256, 0, stream>>>(Xbf, Wt, bq, bk, bv, Qh, Kh, VhT);
        flash_attn_v5<<<dim3(1024), 256, 0, stream>>>(Qh, Kh, VhT, Opart, lpart);
        merge_split<2><<<dim3(4096), 256, 0, stream>>>(Opart, lpart, Ao);
        out_gemm<<<dim3(4, 64), 256, 0, stream>>>(Ao, Wt + (size_t)3 * DM_ * DM_, bo, out);
    } else if (ws_size >= need_bf) {
        unsigned short* Xbf = tail;   // Ao aliases Xbf head (Xbf dead before flash writes Ao)
        unsigned short* Ao = tail;
        prep<<<dim3(4096, 4), 256, 0, stream>>>(q, k, v, Wq, Wk, Wv, Wo, Xbf, Wt);
        qkv_bf<<<dim3(4, 64, 3), 256, 0, stream>>>(Xbf, Wt, bq, bk, bv, Qh, Kh, VhT);
        flash_attn<<<dim3(512), 256, 0, stream>>>(Qh, Kh, VhT, Ao);
        out_gemm<<<dim3(4, 64), 256, 0, stream>>>(Ao, Wt + (size_t)3 * DM_ * DM_, bo, out);
    } else {
        unsigned short* Ao = tail;
        wtrans<<<dim3(8, 8, 4), 256, 0, stream>>>(Wq, Wk, Wv, Wo, Wt);
        qkv_proj<<<dim3(4, 64, 3), 256, 0, stream>>>(q, k, v, Wt, bq, bk, bv, Qh, Kh, VhT);
        flash_attn<<<dim3(512), 256, 0, stream>>>(Qh, Kh, VhT, Ao);
        out_gemm<<<dim3(4, 64), 256, 0, stream>>>(Ao, Wt + (size_t)3 * DM_ * DM_, bo, out);
    }
}

// Round 6
// 243.954 us; speedup vs baseline: 1.5763x; 1.0234x over previous
//
#include <hip/hip_runtime.h>
#include <hip/hip_bf16.h>

#define NHEAD 8
#define DK_ 64
#define DM_ 512
#define S_LEN 4096
#define NTOK 8192

typedef __bf16 bf16x8 __attribute__((ext_vector_type(8)));
typedef float f32x4 __attribute__((ext_vector_type(4)));
typedef float f32x16 __attribute__((ext_vector_type(16)));
typedef unsigned int uint4v __attribute__((ext_vector_type(4)));

__device__ __forceinline__ unsigned short f2bf(float f) {
    union { float f; unsigned u; } x; x.f = f;
    unsigned u = x.u;
    u += 0x7FFFu + ((u >> 16) & 1u);   // round-to-nearest-even (inputs finite)
    return (unsigned short)(u >> 16);
}

// packed f32x2 -> bf16x2 (gfx950 HW op when available; RNE either way)
#if __has_builtin(__builtin_amdgcn_cvt_pk_bf16_f32)
__device__ __forceinline__ unsigned int pkbf(float a, float b) {
    auto r = __builtin_amdgcn_cvt_pk_bf16_f32(a, b);
    unsigned int u; __builtin_memcpy(&u, &r, 4); return u;
}
#else
__device__ __forceinline__ unsigned int pkbf(float a, float b) {
    return (unsigned)f2bf(a) | ((unsigned)f2bf(b) << 16);
}
#endif

#if __has_builtin(__builtin_amdgcn_exp2f)
#define EXP2F(x) __builtin_amdgcn_exp2f(x)
#else
#define EXP2F(x) exp2f(x)
#endif

// lane-half <-> reg exchange: new_a = {a_lo, b_lo}, new_b = {a_hi, b_hi}
#if __has_builtin(__builtin_amdgcn_permlane32_swap)
__device__ __forceinline__ void pl32swap(unsigned int& a, unsigned int& b) {
    auto r = __builtin_amdgcn_permlane32_swap(a, b, false, false);
    a = r[0]; b = r[1];
}
#else
__device__ __forceinline__ void pl32swap(unsigned int& a, unsigned int& b) {
    int lane = threadIdx.x & 63;
    unsigned int ax = __shfl_xor((int)a, 32, 64);
    unsigned int bx = __shfl_xor((int)b, 32, 64);
    unsigned int na = (lane < 32) ? a : bx;
    unsigned int nb = (lane < 32) ? ax : b;
    a = na; b = nb;
}
#endif

// async global->LDS, 16B per lane; LDS dest = wave-uniform base + lane*16
#define GLOAD_LDS16(gptr, ldsbase) \
    __builtin_amdgcn_global_load_lds((const __attribute__((address_space(1))) unsigned int*)(gptr), \
                                     (__attribute__((address_space(3))) unsigned int*)(ldsbase), 16, 0, 0)

// ---------- prep: fused xcvt (z<3) + wtrans (z==3) -> one launch ----------
__global__ __launch_bounds__(256) void prep(const float* __restrict__ q, const float* __restrict__ k,
                                            const float* __restrict__ v,
                                            const float* __restrict__ Wq, const float* __restrict__ Wk,
                                            const float* __restrict__ Wv, const float* __restrict__ Wo,
                                            unsigned short* __restrict__ Xbf, unsigned short* __restrict__ Wt) {
    __shared__ float t[64][65];
    int z = blockIdx.y;
    int tid = threadIdx.x;
    if (z < 3) {
        const float* X = (z == 0) ? q : (z == 1) ? k : v;
        size_t off = (size_t)blockIdx.x * 1024 + tid * 4;
        float4 val = *(const float4*)&X[off];
        uint2 o; o.x = pkbf(val.x, val.y); o.y = pkbf(val.z, val.w);
        *(uint2*)&Xbf[(size_t)z * NTOK * DM_ + off] = o;
        return;
    }
    int bi = blockIdx.x;
    if (bi >= 256) return;
    int zz = bi >> 6;
    int bn = (bi & 7) * 64, bk = ((bi >> 3) & 7) * 64;
    const float* W = (zz == 0) ? Wq : (zz == 1) ? Wk : (zz == 2) ? Wv : Wo;
    unsigned short* out = Wt + (size_t)zz * DM_ * DM_;
    int r0 = tid >> 4, c4 = (tid & 15) * 4;
#pragma unroll
    for (int i = 0; i < 4; i++) {
        int r = r0 + i * 16;
        float4 vv = *(const float4*)&W[(size_t)(bk + r) * DM_ + bn + c4];
        t[r][c4] = vv.x; t[r][c4 + 1] = vv.y; t[r][c4 + 2] = vv.z; t[r][c4 + 3] = vv.w;
    }
    __syncthreads();
    int n0 = tid >> 4, k4 = (tid & 15) * 4;
#pragma unroll
    for (int i = 0; i < 4; i++) {
        int n = n0 + i * 16;
        ushort4 o;
        o.x = f2bf(t[k4 + 0][n]); o.y = f2bf(t[k4 + 1][n]);
        o.z = f2bf(t[k4 + 2][n]); o.w = f2bf(t[k4 + 3][n]);
        *(ushort4*)&out[(size_t)(bn + n) * DM_ + bk + k4] = o;
    }
}

// ---------- standalone wtrans (smallest-ws fallback path) ----------
__global__ __launch_bounds__(256) void wtrans(const float* __restrict__ Wq, const float* __restrict__ Wk,
                                              const float* __restrict__ Wv, const float* __restrict__ Wo,
                                              unsigned short* __restrict__ Wt) {
    int z = blockIdx.z;
    const float* W = (z == 0) ? Wq : (z == 1) ? Wk : (z == 2) ? Wv : Wo;
    unsigned short* out = Wt + (size_t)z * DM_ * DM_;
    __shared__ float t[64][65];
    int bn = blockIdx.x * 64, bk = blockIdx.y * 64;
    int tid = threadIdx.x;
    int r0 = tid >> 4, c4 = (tid & 15) * 4;
#pragma unroll
    for (int i = 0; i < 4; i++) {
        int r = r0 + i * 16;
        float4 v = *(const float4*)&W[(size_t)(bk + r) * DM_ + bn + c4];
        t[r][c4] = v.x; t[r][c4 + 1] = v.y; t[r][c4 + 2] = v.z; t[r][c4 + 3] = v.w;
    }
    __syncthreads();
    int n0 = tid >> 4, k4 = (tid & 15) * 4;
#pragma unroll
    for (int i = 0; i < 4; i++) {
        int n = n0 + i * 16;
        ushort4 o;
        o.x = f2bf(t[k4 + 0][n]); o.y = f2bf(t[k4 + 1][n]);
        o.z = f2bf(t[k4 + 2][n]); o.w = f2bf(t[k4 + 3][n]);
        *(ushort4*)&out[(size_t)(bn + n) * DM_ + bk + k4] = o;
    }
}

// shared epilogue for projection GEMMs
__device__ __forceinline__ void proj_epilogue(int z, f32x4 (&acc)[4][4], const float* bias,
                                              unsigned short* out, float scale,
                                              int m0, int n0, int mb, int nb, int ln, int qd) {
    float bvv[4];
#pragma unroll
    for (int nt = 0; nt < 4; nt++) bvv[nt] = bias[n0 + nb + nt * 16 + ln];
#pragma unroll
    for (int mt = 0; mt < 4; mt++) {
        int mrow0 = m0 + mb + mt * 16 + qd * 4;
        int b = mrow0 >> 12, s = mrow0 & 4095;
#pragma unroll
        for (int nt = 0; nt < 4; nt++) {
            int ncol = n0 + nb + nt * 16 + ln;
            int h = ncol >> 6, d = ncol & 63;
            if (z == 2) {
                uint2 o;
                o.x = pkbf((acc[mt][nt][0] + bvv[nt]) * scale, (acc[mt][nt][1] + bvv[nt]) * scale);
                o.y = pkbf((acc[mt][nt][2] + bvv[nt]) * scale, (acc[mt][nt][3] + bvv[nt]) * scale);
                *(uint2*)&out[((size_t)(b * NHEAD + h) * DK_ + d) * S_LEN + s] = o;
            } else {
#pragma unroll
                for (int r = 0; r < 4; r++)
                    out[((size_t)(b * NHEAD + h) * S_LEN + (s + r)) * DK_ + d] =
                        f2bf((acc[mt][nt][r] + bvv[nt]) * scale);
            }
        }
    }
}

// ---------- fused QKV projection, LDS-DMA staged (m97 pattern) ----------
// Staging via global_load_lds width-16: linear LDS [128][32] bf16 (8KB/tile),
// PRE-SWIZZLED global source (chunk ^= row&3) + swizzled MFMA read
// (chunk = qd^(ln&3)) -> even 8-deep bank-group distribution (b128 minimum).
// Replaces the reg-staged path (Common-mistake #1: compiler never auto-emits
// gload_lds; m93->m97 = +69% on this exact structure).
__global__ __launch_bounds__(256, 3) void qkv_bf(const unsigned short* __restrict__ Xbf,
                                                 const unsigned short* __restrict__ Wt,
                                                 const float* __restrict__ bq, const float* __restrict__ bk,
                                                 const float* __restrict__ bv,
                                                 unsigned short* __restrict__ Qh, unsigned short* __restrict__ Kh,
                                                 unsigned short* __restrict__ VhT) {
    int z = blockIdx.z;
    const unsigned short* X = Xbf + (size_t)z * NTOK * DM_;
    const unsigned short* W = Wt + (size_t)z * DM_ * DM_;
    const float* bias = (z == 0) ? bq : (z == 1) ? bk : bv;
    unsigned short* out = (z == 0) ? Qh : (z == 1) ? Kh : VhT;
    float scale = (z == 0) ? 0.125f * 1.44269504f : 1.0f;

    __shared__ unsigned short As[128 * 32];
    __shared__ unsigned short Bs[128 * 32];
    int tid = threadIdx.x;
    int n0 = blockIdx.x * 128, m0 = blockIdx.y * 128;
    int w = tid >> 6, lane = tid & 63;
    int ln = lane & 15, qd = lane >> 4;
    int mb = (w >> 1) * 64, nb = (w & 1) * 64;

    // staging geometry: per issue a wave covers 16 rows x 32 cols (1KB).
    int lr = lane >> 2;                              // local row 0..15
    int cs = ((lane & 3) ^ (lr & 3)) * 8;            // pre-swizzled source chunk (elems)
    int rdc = (qd ^ (ln & 3)) * 8;                   // swizzled read chunk (elems)

    f32x4 acc[4][4];
#pragma unroll
    for (int i = 0; i < 4; i++)
#pragma unroll
        for (int j = 0; j < 4; j++) { f32x4 zz = {0.f, 0.f, 0.f, 0.f}; acc[i][j] = zz; }

    for (int kk = 0; kk < DM_; kk += 32) {
        __syncthreads();   // previous compute done reading LDS
#pragma unroll
        for (int j = 0; j < 2; j++) {
            int r0 = w * 32 + j * 16;
            GLOAD_LDS16(&X[(size_t)(m0 + r0 + lr) * DM_ + kk + cs], &As[r0 * 32]);
            GLOAD_LDS16(&W[(size_t)(n0 + r0 + lr) * DM_ + kk + cs], &Bs[r0 * 32]);
        }
        __syncthreads();   // drains DMA (vmcnt 0 before barrier)
        bf16x8 af[4], bf[4];
#pragma unroll
        for (int mt = 0; mt < 4; mt++) af[mt] = *(const bf16x8*)&As[(mb + mt * 16 + ln) * 32 + rdc];
#pragma unroll
        for (int nt = 0; nt < 4; nt++) bf[nt] = *(const bf16x8*)&Bs[(nb + nt * 16 + ln) * 32 + rdc];
#pragma unroll
        for (int mt = 0; mt < 4; mt++)
#pragma unroll
            for (int nt = 0; nt < 4; nt++)
                acc[mt][nt] = __builtin_amdgcn_mfma_f32_16x16x32_bf16(af[mt], bf[nt], acc[mt][nt], 0, 0, 0);
    }
    proj_epilogue(z, acc, bias, out, scale, m0, n0, mb, nb, ln, qd);
}

// ---------- fallback fused QKV projection from fp32 X (small ws) ----------
__global__ __launch_bounds__(256, 3) void qkv_proj(const float* __restrict__ xq, const float* __restrict__ xk,
                                                   const float* __restrict__ xv, const unsigned short* __restrict__ Wt,
                                                   const float* __restrict__ bq, const float* __restrict__ bk,
                                                   const float* __restrict__ bv,
                                                   unsigned short* __restrict__ Qh, unsigned short* __restrict__ Kh,
                                                   unsigned short* __restrict__ VhT) {
    int z = blockIdx.z;
    const float* X = (z == 0) ? xq : (z == 1) ? xk : xv;
    const unsigned short* W = Wt + (size_t)z * DM_ * DM_;
    const float* bias = (z == 0) ? bq : (z == 1) ? bk : bv;
    unsigned short* out = (z == 0) ? Qh : (z == 1) ? Kh : VhT;
    float scale = (z == 0) ? 0.125f * 1.44269504f : 1.0f;

    __shared__ unsigned short As[128 * 40];
    __shared__ unsigned short Bs[128 * 40];
    int tid = threadIdx.x;
    int n0 = blockIdx.x * 128, m0 = blockIdx.y * 128;
    int w = tid >> 6, lane = tid & 63;
    int ln = lane & 15, qd = lane >> 4;
    int mb = (w >> 1) * 64, nb = (w & 1) * 64;

    f32x4 acc[4][4];
#pragma unroll
    for (int i = 0; i < 4; i++)
#pragma unroll
        for (int j = 0; j < 4; j++) { f32x4 zz = {0.f, 0.f, 0.f, 0.f}; acc[i][j] = zz; }

    for (int kk = 0; kk < DM_; kk += 32) {
        __syncthreads();
#pragma unroll
        for (int i = 0; i < 4; i++) {
            int idx = i * 256 + tid;
            int row = idx >> 3, k4 = (idx & 7) * 4;
            float4 v = *(const float4*)&X[(size_t)(m0 + row) * DM_ + kk + k4];
            uint2 o; o.x = pkbf(v.x, v.y); o.y = pkbf(v.z, v.w);
            *(uint2*)&As[row * 40 + k4] = o;
        }
#pragma unroll
        for (int i = 0; i < 2; i++) {
            int idx = i * 256 + tid;
            int row = idx >> 2, k8 = (idx & 3) * 8;
            uint4 v = *(const uint4*)&W[(size_t)(n0 + row) * DM_ + kk + k8];
            *(uint4*)&Bs[row * 40 + k8] = v;
        }
        __syncthreads();
        bf16x8 af[4], bf[4];
#pragma unroll
        for (int mt = 0; mt < 4; mt++) af[mt] = *(const bf16x8*)&As[(mb + mt * 16 + ln) * 40 + qd * 8];
#pragma unroll
        for (int nt = 0; nt < 4; nt++) bf[nt] = *(const bf16x8*)&Bs[(nb + nt * 16 + ln) * 40 + qd * 8];
#pragma unroll
        for (int mt = 0; mt < 4; mt++)
#pragma unroll
            for (int nt = 0; nt < 4; nt++)
                acc[mt][nt] = __builtin_amdgcn_mfma_f32_16x16x32_bf16(af[mt], bf[nt], acc[mt][nt], 0, 0, 0);
    }
    proj_epilogue(z, acc, bias, out, scale, m0, n0, mb, nb, ln, qd);
}

// ---------- flash attention (legacy single-pass, small-ws fallback) ----------
__global__ __launch_bounds__(256, 2) void flash_attn(const unsigned short* __restrict__ Qh,
                                                     const unsigned short* __restrict__ Kh,
                                                     const unsigned short* __restrict__ VhT,
                                                     unsigned short* __restrict__ Ao) {
    __shared__ unsigned short Ks[2][64 * 64];     // 16 KB
    __shared__ unsigned short Vs[2][64 * 64];     // 16 KB
    int i = blockIdx.x;
    int bh = (i & 7) + 8 * ((i >> 3) & 1);
    int qb = i >> 4;
    int tid = threadIdx.x;
    int w = tid >> 6, lane = tid & 63;
    int ln = lane & 31, hf = lane >> 5;
    int swz = ln & 7;
    int q0 = qb * 128 + w * 32;
    const unsigned short* Qp = Qh + (size_t)bh * S_LEN * DK_;
    const unsigned short* Kp = Kh + (size_t)bh * S_LEN * DK_;
    const unsigned short* Vp = VhT + (size_t)bh * DK_ * S_LEN;

    int sr = lane >> 3;
    int sc = (lane & 7) ^ sr;
    const unsigned short* ksrc = Kp + (size_t)(w * 16 + sr) * DK_ + sc * 8;
    const unsigned short* vsrc = Vp + (size_t)(w * 16 + sr) * S_LEN + sc * 8;

    bf16x8 qf[4];
#pragma unroll
    for (int s = 0; s < 4; s++)
        qf[s] = *(const bf16x8*)&Qp[(size_t)(q0 + ln) * DK_ + s * 16 + hf * 8];

    f32x16 oacc[2];
    { f32x16 z = {0.f}; oacc[0] = z; oacc[1] = z; }
    float lsum = 0.f;

    GLOAD_LDS16(ksrc, &Ks[0][w * 1024]);
    GLOAD_LDS16(ksrc + (size_t)8 * DK_, &Ks[0][w * 1024 + 512]);
    GLOAD_LDS16(vsrc, &Vs[0][w * 1024]);
    GLOAD_LDS16(vsrc + (size_t)8 * S_LEN, &Vs[0][w * 1024 + 512]);

    int p = 0;
    for (int ks = 0; ks < S_LEN; ks += 64, p ^= 1) {
        __syncthreads();
        if (ks + 64 < S_LEN) {
            const unsigned short* kn = ksrc + (size_t)(ks + 64) * DK_;
            const unsigned short* vn = vsrc + (ks + 64);
            GLOAD_LDS16(kn, &Ks[p ^ 1][w * 1024]);
            GLOAD_LDS16(kn + (size_t)8 * DK_, &Ks[p ^ 1][w * 1024 + 512]);
            GLOAD_LDS16(vn, &Vs[p ^ 1][w * 1024]);
            GLOAD_LDS16(vn + (size_t)8 * S_LEN, &Vs[p ^ 1][w * 1024 + 512]);
        }
        const unsigned short* KsT = &Ks[p][0];
        const unsigned short* VsT = &Vs[p][0];

#pragma unroll
        for (int kb = 0; kb < 2; kb++) {
            f32x16 st = {0.f};
#pragma unroll
            for (int s = 0; s < 4; s++) {
                bf16x8 kf = *(const bf16x8*)&KsT[(kb * 32 + ln) * 64 + ((2 * s + hf) ^ swz) * 8];
                st = __builtin_amdgcn_mfma_f32_32x32x16_bf16(kf, qf[s], st, 0, 0, 0);
            }
            float e[16];
#pragma unroll
            for (int r = 0; r < 16; r++) e[r] = EXP2F(st[r]);
            lsum += ((e[0] + e[1]) + (e[2] + e[3])) + ((e[4] + e[5]) + (e[6] + e[7]))
                  + ((e[8] + e[9]) + (e[10] + e[11])) + ((e[12] + e[13]) + (e[14] + e[15]));
            unsigned int g[8];
#pragma unroll
            for (int gi = 0; gi < 8; gi++) g[gi] = pkbf(e[2 * gi], e[2 * gi + 1]);
            pl32swap(g[0], g[2]); pl32swap(g[1], g[3]);
            pl32swap(g[4], g[6]); pl32swap(g[5], g[7]);
            bf16x8 b0, b1;
            { uint4v t = {g[0], g[1], g[2], g[3]}; __builtin_memcpy(&b0, &t, 16); }
            { uint4v t = {g[4], g[5], g[6], g[7]}; __builtin_memcpy(&b1, &t, 16); }
#pragma unroll
            for (int dt = 0; dt < 2; dt++) {
                int s0 = kb * 2;
                bf16x8 vf0 = *(const bf16x8*)&VsT[(dt * 32 + ln) * 64 + ((2 * s0 + hf) ^ swz) * 8];
                bf16x8 vf1 = *(const bf16x8*)&VsT[(dt * 32 + ln) * 64 + ((2 * s0 + 2 + hf) ^ swz) * 8];
                oacc[dt] = __builtin_amdgcn_mfma_f32_32x32x16_bf16(vf0, b0, oacc[dt], 0, 0, 0);
                oacc[dt] = __builtin_amdgcn_mfma_f32_32x32x16_bf16(vf1, b1, oacc[dt], 0, 0, 0);
            }
        }
    }

    float ltot = lsum + __shfl_xor(lsum, 32, 64);
    float inv = 1.0f / ltot;

    int bb = bh >> 3, hh = bh & 7;
    int token = bb * S_LEN + q0 + ln;
#pragma unroll
    for (int dt = 0; dt < 2; dt++)
#pragma unroll
        for (int gi = 0; gi < 8; gi++) {
            int d = dt * 32 + 2 * (gi & 1) + 8 * (gi >> 1) + 4 * hf;
            unsigned int o = pkbf(oacc[dt][2 * gi] * inv, oacc[dt][2 * gi + 1] * inv);
            *(unsigned int*)&Ao[(size_t)token * DM_ + hh * DK_ + d] = o;
        }
}

// ---------- split-K flash attention (32 q/wave, 2-way key split) ----------
// Round-1 proven shape (99.5 us) restored VERBATIM: v5's pipeline/zero-C/
// setprio bundle measured -4.7% (r5 post-mortem) — reverted.
__global__ __launch_bounds__(256, 4) void flash_attn_sp(const unsigned short* __restrict__ Qh,
                                                        const unsigned short* __restrict__ Kh,
                                                        const unsigned short* __restrict__ VhT,
                                                        float* __restrict__ Opart,
                                                        float* __restrict__ lpart) {
    __shared__ unsigned short Ks[2][64 * 64];
    __shared__ unsigned short Vs[2][64 * 64];
    int i = blockIdx.x;
    int bh = (i & 7) + 8 * ((i >> 3) & 1);
    int qb = (i >> 4) & 31;
    int sp = i >> 9;
    int ks0 = sp * (S_LEN / 2);
    int ks1 = ks0 + (S_LEN / 2);
    int tid = threadIdx.x;
    int w = tid >> 6, lane = tid & 63;
    int ln = lane & 31, hf = lane >> 5;
    int swz = ln & 7;
    int q0 = qb * 128 + w * 32;
    const unsigned short* Qp = Qh + (size_t)bh * S_LEN * DK_;
    const unsigned short* Kp = Kh + (size_t)bh * S_LEN * DK_;
    const unsigned short* Vp = VhT + (size_t)bh * DK_ * S_LEN;

    int sr = lane >> 3;
    int sc = (lane & 7) ^ sr;
    const unsigned short* ksrc = Kp + (size_t)(w * 16 + sr) * DK_ + sc * 8;
    const unsigned short* vsrc = Vp + (size_t)(w * 16 + sr) * S_LEN + sc * 8;

    bf16x8 qf[4];
#pragma unroll
    for (int s = 0; s < 4; s++)
        qf[s] = *(const bf16x8*)&Qp[(size_t)(q0 + ln) * DK_ + s * 16 + hf * 8];

    f32x16 oacc[2];
    { f32x16 z = {0.f}; oacc[0] = z; oacc[1] = z; }
    float lsum = 0.f;

    GLOAD_LDS16(ksrc + (size_t)ks0 * DK_, &Ks[0][w * 1024]);
    GLOAD_LDS16(ksrc + (size_t)(ks0 + 8) * DK_, &Ks[0][w * 1024 + 512]);
    GLOAD_LDS16(vsrc + ks0, &Vs[0][w * 1024]);
    GLOAD_LDS16(vsrc + ks0 + (size_t)8 * S_LEN, &Vs[0][w * 1024 + 512]);

    int p = 0;
    for (int ks = ks0; ks < ks1; ks += 64, p ^= 1) {
        __syncthreads();
        if (ks + 64 < ks1) {
            const unsigned short* kn = ksrc + (size_t)(ks + 64) * DK_;
            const unsigned short* vn = vsrc + (ks + 64);
            GLOAD_LDS16(kn, &Ks[p ^ 1][w * 1024]);
            GLOAD_LDS16(kn + (size_t)8 * DK_, &Ks[p ^ 1][w * 1024 + 512]);
            GLOAD_LDS16(vn, &Vs[p ^ 1][w * 1024]);
            GLOAD_LDS16(vn + (size_t)8 * S_LEN, &Vs[p ^ 1][w * 1024 + 512]);
        }
        const unsigned short* KsT = &Ks[p][0];
        const unsigned short* VsT = &Vs[p][0];

#pragma unroll
        for (int kb = 0; kb < 2; kb++) {
            f32x16 st = {0.f};
#pragma unroll
            for (int s = 0; s < 4; s++) {
                bf16x8 kf = *(const bf16x8*)&KsT[(kb * 32 + ln) * 64 + ((2 * s + hf) ^ swz) * 8];
                st = __builtin_amdgcn_mfma_f32_32x32x16_bf16(kf, qf[s], st, 0, 0, 0);
            }
            float e[16];
#pragma unroll
            for (int r = 0; r < 16; r++) e[r] = EXP2F(st[r]);
            lsum += ((e[0] + e[1]) + (e[2] + e[3])) + ((e[4] + e[5]) + (e[6] + e[7]))
                  + ((e[8] + e[9]) + (e[10] + e[11])) + ((e[12] + e[13]) + (e[14] + e[15]));
            unsigned int g[8];
#pragma unroll
            for (int gi = 0; gi < 8; gi++) g[gi] = pkbf(e[2 * gi], e[2 * gi + 1]);
            pl32swap(g[0], g[2]); pl32swap(g[1], g[3]);
            pl32swap(g[4], g[6]); pl32swap(g[5], g[7]);
            bf16x8 b0, b1;
            { uint4v t = {g[0], g[1], g[2], g[3]}; __builtin_memcpy(&b0, &t, 16); }
            { uint4v t = {g[4], g[5], g[6], g[7]}; __builtin_memcpy(&b1, &t, 16); }
#pragma unroll
            for (int dt = 0; dt < 2; dt++) {
                int s0 = kb * 2;
                bf16x8 vf0 = *(const bf16x8*)&VsT[(dt * 32 + ln) * 64 + ((2 * s0 + hf) ^ swz) * 8];
                bf16x8 vf1 = *(const bf16x8*)&VsT[(dt * 32 + ln) * 64 + ((2 * s0 + 2 + hf) ^ swz) * 8];
                oacc[dt] = __builtin_amdgcn_mfma_f32_32x32x16_bf16(vf0, b0, oacc[dt], 0, 0, 0);
                oacc[dt] = __builtin_amdgcn_mfma_f32_32x32x16_bf16(vf1, b1, oacc[dt], 0, 0, 0);
            }
        }
    }

    float ltot = lsum + __shfl_xor(lsum, 32, 64);
    if (hf == 0)
        lpart[(size_t)sp * (16 * S_LEN) + (size_t)bh * S_LEN + q0 + ln] = ltot;

    int bb = bh >> 3, hh = bh & 7;
    int token = bb * S_LEN + q0 + ln;
    float* op = Opart + (size_t)sp * NTOK * DM_;
#pragma unroll
    for (int dt = 0; dt < 2; dt++)
#pragma unroll
        for (int gi = 0; gi < 8; gi++) {
            int d = dt * 32 + 2 * (gi & 1) + 8 * (gi >> 1) + 4 * hf;
            float2 o; o.x = oacc[dt][2 * gi]; o.y = oacc[dt][2 * gi + 1];
            *(float2*)&op[(size_t)token * DM_ + hh * DK_ + d] = o;
        }
}

// ---------- merge NSP key-split partials -> normalized bf16 Ao ----------
template <int NSP>
__global__ __launch_bounds__(256) void merge_split(const float* __restrict__ Opart,
                                                   const float* __restrict__ lpart,
                                                   unsigned short* __restrict__ Ao) {
    size_t e = ((size_t)blockIdx.x * 256 + threadIdx.x) * 4;   // 4 f32 elems, same head
    int token = (int)(e >> 9);
    int c = (int)(e & 511);
    int hh = c >> 6;
    int bb = token >> 12, s = token & 4095;
    size_t li = (size_t)(bb * NHEAD + hh) * S_LEN + s;
    float ltot = 0.f;
#pragma unroll
    for (int j = 0; j < NSP; j++) ltot += lpart[(size_t)j * (16 * S_LEN) + li];
    float inv = 1.0f / ltot;
    float4 a = *(const float4*)&Opart[e];
#pragma unroll
    for (int j = 1; j < NSP; j++) {
        float4 b = *(const float4*)&Opart[(size_t)j * NTOK * DM_ + e];
        a.x += b.x; a.y += b.y; a.z += b.z; a.w += b.w;
    }
    uint2 o;
    o.x = pkbf(a.x * inv, a.y * inv);
    o.y = pkbf(a.z * inv, a.w * inv);
    *(uint2*)&Ao[e] = o;
}

// ---------- output GEMM: out = Ao(bf16)@Wo + bo, fp32 out (LDS-DMA staged) ----------
__global__ __launch_bounds__(256, 3) void out_gemm(const unsigned short* __restrict__ A,
                                                   const unsigned short* __restrict__ Wt,
                                                   const float* __restrict__ bias, float* __restrict__ out) {
    __shared__ unsigned short As[128 * 32];
    __shared__ unsigned short Bs[128 * 32];
    int tid = threadIdx.x;
    int n0 = blockIdx.x * 128, m0 = blockIdx.y * 128;
    int w = tid >> 6, lane = tid & 63;
    int ln = lane & 15, qd = lane >> 4;
    int mb = (w >> 1) * 64, nb = (w & 1) * 64;

    int lr = lane >> 2;
    int cs = ((lane & 3) ^ (lr & 3)) * 8;
    int rdc = (qd ^ (ln & 3)) * 8;

    f32x4 acc[4][4];
#pragma unroll
    for (int i = 0; i < 4; i++)
#pragma unroll
        for (int j = 0; j < 4; j++) { f32x4 z = {0.f, 0.f, 0.f, 0.f}; acc[i][j] = z; }

    for (int kk = 0; kk < DM_; kk += 32) {
        __syncthreads();
#pragma unroll
        for (int j = 0; j < 2; j++) {
            int r0 = w * 32 + j * 16;
            GLOAD_LDS16(&A[(size_t)(m0 + r0 + lr) * DM_ + kk + cs], &As[r0 * 32]);
            GLOAD_LDS16(&Wt[(size_t)(n0 + r0 + lr) * DM_ + kk + cs], &Bs[r0 * 32]);
        }
        __syncthreads();
        bf16x8 af[4], bf[4];
#pragma unroll
        for (int mt = 0; mt < 4; mt++) af[mt] = *(const bf16x8*)&As[(mb + mt * 16 + ln) * 32 + rdc];
#pragma unroll
        for (int nt = 0; nt < 4; nt++) bf[nt] = *(const bf16x8*)&Bs[(nb + nt * 16 + ln) * 32 + rdc];
#pragma unroll
        for (int mt = 0; mt < 4; mt++)
#pragma unroll
            for (int nt = 0; nt < 4; nt++)
                acc[mt][nt] = __builtin_amdgcn_mfma_f32_16x16x32_bf16(af[mt], bf[nt], acc[mt][nt], 0, 0, 0);
    }

    float bv[4];
#pragma unroll
    for (int nt = 0; nt < 4; nt++) bv[nt] = bias[n0 + nb + nt * 16 + ln];
#pragma unroll
    for (int mt = 0; mt < 4; mt++) {
        int mrow0 = m0 + mb + mt * 16 + qd * 4;
#pragma unroll
        for (int nt = 0; nt < 4; nt++) {
            int ncol = n0 + nb + nt * 16 + ln;
#pragma unroll
            for (int r = 0; r < 4; r++)
                out[(size_t)(mrow0 + r) * DM_ + ncol] = acc[mt][nt][r] + bv[nt];
        }
    }
}

extern "C" void kernel_launch(void* const* d_in, const int* in_sizes, int n_in,
                              void* d_out, int out_size, void* d_ws, size_t ws_size,
                              hipStream_t stream) {
    const float* q  = (const float*)d_in[0];
    const float* k  = (const float*)d_in[1];
    const float* v  = (const float*)d_in[2];
    const float* Wq = (const float*)d_in[3];
    const float* bq = (const float*)d_in[4];
    const float* Wk = (const float*)d_in[5];
    const float* bk = (const float*)d_in[6];
    const float* Wv = (const float*)d_in[7];
    const float* bv = (const float*)d_in[8];
    const float* Wo = (const float*)d_in[9];
    const float* bo = (const float*)d_in[10];
    float* out = (float*)d_out;

    unsigned short* Wt  = (unsigned short*)d_ws;
    unsigned short* Qh  = Wt + (size_t)4 * DM_ * DM_;
    unsigned short* Kh  = Qh + (size_t)NTOK * DM_;
    unsigned short* VhT = Kh + (size_t)NTOK * DM_;
    unsigned short* tail = VhT + (size_t)NTOK * DM_;

    size_t head_b  = ((size_t)4 * DM_ * DM_ + (size_t)3 * NTOK * DM_) * 2;
    size_t opart_b2 = (size_t)2 * NTOK * DM_ * 4;
    size_t lpart_b2 = (size_t)2 * 16 * S_LEN * 4;
    size_t ao_b     = (size_t)NTOK * DM_ * 2;
    size_t need_sp2 = head_b + opart_b2 + lpart_b2 + ao_b;
    size_t need_bf  = ((size_t)4 * DM_ * DM_ + (size_t)6 * NTOK * DM_) * 2;

    if (ws_size >= need_sp2) {
        // tail layout: [Opart 2x f32][lpart 2x][Ao bf16]; Xbf aliases head of Opart
        float* Opart = (float*)tail;
        float* lpart = Opart + (size_t)2 * NTOK * DM_;
        unsigned short* Ao = (unsigned short*)(lpart + (size_t)2 * 16 * S_LEN);
        unsigned short* Xbf = tail;
        prep<<<dim3(4096, 4), 256, 0, stream>>>(q, k, v, Wq, Wk, Wv, Wo, Xbf, Wt);
        qkv_bf<<<dim3(4, 64, 3), 256, 0, stream>>>(Xbf, Wt, bq, bk, bv, Qh, Kh, VhT);
        flash_attn_sp<<<dim3(1024), 256, 0, stream>>>(Qh, Kh, VhT, Opart, lpart);
        merge_split<2><<<dim3(4096), 256, 0, stream>>>(Opart, lpart, Ao);
        out_gemm<<<dim3(4, 64), 256, 0, stream>>>(Ao, Wt + (size_t)3 * DM_ * DM_, bo, out);
    } else if (ws_size >= need_bf) {
        unsigned short* Xbf = tail;   // Ao aliases Xbf head (Xbf dead before flash writes Ao)
        unsigned short* Ao = tail;
        prep<<<dim3(4096, 4), 256, 0, stream>>>(q, k, v, Wq, Wk, Wv, Wo, Xbf, Wt);
        qkv_bf<<<dim3(4, 64, 3), 256, 0, stream>>>(Xbf, Wt, bq, bk, bv, Qh, Kh, VhT);
        flash_attn<<<dim3(512), 256, 0, stream>>>(Qh, Kh, VhT, Ao);
        out_gemm<<<dim3(4, 64), 256, 0, stream>>>(Ao, Wt + (size_t)3 * DM_ * DM_, bo, out);
    } else {
        unsigned short* Ao = tail;
        wtrans<<<dim3(8, 8, 4), 256, 0, stream>>>(Wq, Wk, Wv, Wo, Wt);
        qkv_proj<<<dim3(4, 64, 3), 256, 0, stream>>>(q, k, v, Wt, bq, bk, bv, Qh, Kh, VhT);
        flash_attn<<<dim3(512), 256, 0, stream>>>(Qh, Kh, VhT, Ao);
        out_gemm<<<dim3(4, 64), 256, 0, stream>>>(Ao, Wt + (size_t)3 * DM_ * DM_, bo, out);
    }
}

// Round 7
// 240.064 us; speedup vs baseline: 1.6019x; 1.0162x over previous
//
#include <hip/hip_runtime.h>
#include <hip/hip_bf16.h>

#define NHEAD 8
#define DK_ 64
#define DM_ 512
#define S_LEN 4096
#define NTOK 8192

typedef __bf16 bf16x8 __attribute__((ext_vector_type(8)));
typedef float f32x4 __attribute__((ext_vector_type(4)));
typedef float f32x16 __attribute__((ext_vector_type(16)));
typedef unsigned int uint4v __attribute__((ext_vector_type(4)));

__device__ __forceinline__ unsigned short f2bf(float f) {
    union { float f; unsigned u; } x; x.f = f;
    unsigned u = x.u;
    u += 0x7FFFu + ((u >> 16) & 1u);   // round-to-nearest-even (inputs finite)
    return (unsigned short)(u >> 16);
}

// packed f32x2 -> bf16x2 (gfx950 HW op when available; RNE either way)
#if __has_builtin(__builtin_amdgcn_cvt_pk_bf16_f32)
__device__ __forceinline__ unsigned int pkbf(float a, float b) {
    auto r = __builtin_amdgcn_cvt_pk_bf16_f32(a, b);
    unsigned int u; __builtin_memcpy(&u, &r, 4); return u;
}
#else
__device__ __forceinline__ unsigned int pkbf(float a, float b) {
    return (unsigned)f2bf(a) | ((unsigned)f2bf(b) << 16);
}
#endif

#if __has_builtin(__builtin_amdgcn_exp2f)
#define EXP2F(x) __builtin_amdgcn_exp2f(x)
#else
#define EXP2F(x) exp2f(x)
#endif

// lane-half <-> reg exchange: new_a = {a_lo, b_lo}, new_b = {a_hi, b_hi}
#if __has_builtin(__builtin_amdgcn_permlane32_swap)
__device__ __forceinline__ void pl32swap(unsigned int& a, unsigned int& b) {
    auto r = __builtin_amdgcn_permlane32_swap(a, b, false, false);
    a = r[0]; b = r[1];
}
#else
__device__ __forceinline__ void pl32swap(unsigned int& a, unsigned int& b) {
    int lane = threadIdx.x & 63;
    unsigned int ax = __shfl_xor((int)a, 32, 64);
    unsigned int bx = __shfl_xor((int)b, 32, 64);
    unsigned int na = (lane < 32) ? a : bx;
    unsigned int nb = (lane < 32) ? ax : b;
    a = na; b = nb;
}
#endif

// async global->LDS, 16B per lane; LDS dest = wave-uniform base + lane*16
#define GLOAD_LDS16(gptr, ldsbase) \
    __builtin_amdgcn_global_load_lds((const __attribute__((address_space(1))) unsigned int*)(gptr), \
                                     (__attribute__((address_space(3))) unsigned int*)(ldsbase), 16, 0, 0)

// ---------- prep: fused xcvt (z<3) + wtrans (z==3) -> one launch ----------
__global__ __launch_bounds__(256) void prep(const float* __restrict__ q, const float* __restrict__ k,
                                            const float* __restrict__ v,
                                            const float* __restrict__ Wq, const float* __restrict__ Wk,
                                            const float* __restrict__ Wv, const float* __restrict__ Wo,
                                            unsigned short* __restrict__ Xbf, unsigned short* __restrict__ Wt) {
    __shared__ float t[64][65];
    int z = blockIdx.y;
    int tid = threadIdx.x;
    if (z < 3) {
        const float* X = (z == 0) ? q : (z == 1) ? k : v;
        size_t off = (size_t)blockIdx.x * 1024 + tid * 4;
        float4 val = *(const float4*)&X[off];
        uint2 o; o.x = pkbf(val.x, val.y); o.y = pkbf(val.z, val.w);
        *(uint2*)&Xbf[(size_t)z * NTOK * DM_ + off] = o;
        return;
    }
    int bi = blockIdx.x;
    if (bi >= 256) return;
    int zz = bi >> 6;
    int bn = (bi & 7) * 64, bk = ((bi >> 3) & 7) * 64;
    const float* W = (zz == 0) ? Wq : (zz == 1) ? Wk : (zz == 2) ? Wv : Wo;
    unsigned short* out = Wt + (size_t)zz * DM_ * DM_;
    int r0 = tid >> 4, c4 = (tid & 15) * 4;
#pragma unroll
    for (int i = 0; i < 4; i++) {
        int r = r0 + i * 16;
        float4 vv = *(const float4*)&W[(size_t)(bk + r) * DM_ + bn + c4];
        t[r][c4] = vv.x; t[r][c4 + 1] = vv.y; t[r][c4 + 2] = vv.z; t[r][c4 + 3] = vv.w;
    }
    __syncthreads();
    int n0 = tid >> 4, k4 = (tid & 15) * 4;
#pragma unroll
    for (int i = 0; i < 4; i++) {
        int n = n0 + i * 16;
        ushort4 o;
        o.x = f2bf(t[k4 + 0][n]); o.y = f2bf(t[k4 + 1][n]);
        o.z = f2bf(t[k4 + 2][n]); o.w = f2bf(t[k4 + 3][n]);
        *(ushort4*)&out[(size_t)(bn + n) * DM_ + bk + k4] = o;
    }
}

// ---------- standalone wtrans (smallest-ws fallback path) ----------
__global__ __launch_bounds__(256) void wtrans(const float* __restrict__ Wq, const float* __restrict__ Wk,
                                              const float* __restrict__ Wv, const float* __restrict__ Wo,
                                              unsigned short* __restrict__ Wt) {
    int z = blockIdx.z;
    const float* W = (z == 0) ? Wq : (z == 1) ? Wk : (z == 2) ? Wv : Wo;
    unsigned short* out = Wt + (size_t)z * DM_ * DM_;
    __shared__ float t[64][65];
    int bn = blockIdx.x * 64, bk = blockIdx.y * 64;
    int tid = threadIdx.x;
    int r0 = tid >> 4, c4 = (tid & 15) * 4;
#pragma unroll
    for (int i = 0; i < 4; i++) {
        int r = r0 + i * 16;
        float4 v = *(const float4*)&W[(size_t)(bk + r) * DM_ + bn + c4];
        t[r][c4] = v.x; t[r][c4 + 1] = v.y; t[r][c4 + 2] = v.z; t[r][c4 + 3] = v.w;
    }
    __syncthreads();
    int n0 = tid >> 4, k4 = (tid & 15) * 4;
#pragma unroll
    for (int i = 0; i < 4; i++) {
        int n = n0 + i * 16;
        ushort4 o;
        o.x = f2bf(t[k4 + 0][n]); o.y = f2bf(t[k4 + 1][n]);
        o.z = f2bf(t[k4 + 2][n]); o.w = f2bf(t[k4 + 3][n]);
        *(ushort4*)&out[(size_t)(bn + n) * DM_ + bk + k4] = o;
    }
}

// shared epilogue for projection GEMMs
__device__ __forceinline__ void proj_epilogue(int z, f32x4 (&acc)[4][4], const float* bias,
                                              unsigned short* out, float scale,
                                              int m0, int n0, int mb, int nb, int ln, int qd) {
    float bvv[4];
#pragma unroll
    for (int nt = 0; nt < 4; nt++) bvv[nt] = bias[n0 + nb + nt * 16 + ln];
#pragma unroll
    for (int mt = 0; mt < 4; mt++) {
        int mrow0 = m0 + mb + mt * 16 + qd * 4;
        int b = mrow0 >> 12, s = mrow0 & 4095;
#pragma unroll
        for (int nt = 0; nt < 4; nt++) {
            int ncol = n0 + nb + nt * 16 + ln;
            int h = ncol >> 6, d = ncol & 63;
            if (z == 2) {
                uint2 o;
                o.x = pkbf((acc[mt][nt][0] + bvv[nt]) * scale, (acc[mt][nt][1] + bvv[nt]) * scale);
                o.y = pkbf((acc[mt][nt][2] + bvv[nt]) * scale, (acc[mt][nt][3] + bvv[nt]) * scale);
                *(uint2*)&out[((size_t)(b * NHEAD + h) * DK_ + d) * S_LEN + s] = o;
            } else {
#pragma unroll
                for (int r = 0; r < 4; r++)
                    out[((size_t)(b * NHEAD + h) * S_LEN + (s + r)) * DK_ + d] =
                        f2bf((acc[mt][nt][r] + bvv[nt]) * scale);
            }
        }
    }
}

// ---------- fused QKV projection, LDS-DMA staged (m97 pattern) ----------
__global__ __launch_bounds__(256, 3) void qkv_bf(const unsigned short* __restrict__ Xbf,
                                                 const unsigned short* __restrict__ Wt,
                                                 const float* __restrict__ bq, const float* __restrict__ bk,
                                                 const float* __restrict__ bv,
                                                 unsigned short* __restrict__ Qh, unsigned short* __restrict__ Kh,
                                                 unsigned short* __restrict__ VhT) {
    int z = blockIdx.z;
    const unsigned short* X = Xbf + (size_t)z * NTOK * DM_;
    const unsigned short* W = Wt + (size_t)z * DM_ * DM_;
    const float* bias = (z == 0) ? bq : (z == 1) ? bk : bv;
    unsigned short* out = (z == 0) ? Qh : (z == 1) ? Kh : VhT;
    float scale = (z == 0) ? 0.125f * 1.44269504f : 1.0f;

    __shared__ unsigned short As[128 * 32];
    __shared__ unsigned short Bs[128 * 32];
    int tid = threadIdx.x;
    int n0 = blockIdx.x * 128, m0 = blockIdx.y * 128;
    int w = tid >> 6, lane = tid & 63;
    int ln = lane & 15, qd = lane >> 4;
    int mb = (w >> 1) * 64, nb = (w & 1) * 64;

    int lr = lane >> 2;                              // local row 0..15
    int cs = ((lane & 3) ^ (lr & 3)) * 8;            // pre-swizzled source chunk (elems)
    int rdc = (qd ^ (ln & 3)) * 8;                   // swizzled read chunk (elems)

    f32x4 acc[4][4];
#pragma unroll
    for (int i = 0; i < 4; i++)
#pragma unroll
        for (int j = 0; j < 4; j++) { f32x4 zz = {0.f, 0.f, 0.f, 0.f}; acc[i][j] = zz; }

    for (int kk = 0; kk < DM_; kk += 32) {
        __syncthreads();
#pragma unroll
        for (int j = 0; j < 2; j++) {
            int r0 = w * 32 + j * 16;
            GLOAD_LDS16(&X[(size_t)(m0 + r0 + lr) * DM_ + kk + cs], &As[r0 * 32]);
            GLOAD_LDS16(&W[(size_t)(n0 + r0 + lr) * DM_ + kk + cs], &Bs[r0 * 32]);
        }
        __syncthreads();
        bf16x8 af[4], bf[4];
#pragma unroll
        for (int mt = 0; mt < 4; mt++) af[mt] = *(const bf16x8*)&As[(mb + mt * 16 + ln) * 32 + rdc];
#pragma unroll
        for (int nt = 0; nt < 4; nt++) bf[nt] = *(const bf16x8*)&Bs[(nb + nt * 16 + ln) * 32 + rdc];
#pragma unroll
        for (int mt = 0; mt < 4; mt++)
#pragma unroll
            for (int nt = 0; nt < 4; nt++)
                acc[mt][nt] = __builtin_amdgcn_mfma_f32_16x16x32_bf16(af[mt], bf[nt], acc[mt][nt], 0, 0, 0);
    }
    proj_epilogue(z, acc, bias, out, scale, m0, n0, mb, nb, ln, qd);
}

// ---------- fallback fused QKV projection from fp32 X (small ws) ----------
__global__ __launch_bounds__(256, 3) void qkv_proj(const float* __restrict__ xq, const float* __restrict__ xk,
                                                   const float* __restrict__ xv, const unsigned short* __restrict__ Wt,
                                                   const float* __restrict__ bq, const float* __restrict__ bk,
                                                   const float* __restrict__ bv,
                                                   unsigned short* __restrict__ Qh, unsigned short* __restrict__ Kh,
                                                   unsigned short* __restrict__ VhT) {
    int z = blockIdx.z;
    const float* X = (z == 0) ? xq : (z == 1) ? xk : xv;
    const unsigned short* W = Wt + (size_t)z * DM_ * DM_;
    const float* bias = (z == 0) ? bq : (z == 1) ? bk : bv;
    unsigned short* out = (z == 0) ? Qh : (z == 1) ? Kh : VhT;
    float scale = (z == 0) ? 0.125f * 1.44269504f : 1.0f;

    __shared__ unsigned short As[128 * 40];
    __shared__ unsigned short Bs[128 * 40];
    int tid = threadIdx.x;
    int n0 = blockIdx.x * 128, m0 = blockIdx.y * 128;
    int w = tid >> 6, lane = tid & 63;
    int ln = lane & 15, qd = lane >> 4;
    int mb = (w >> 1) * 64, nb = (w & 1) * 64;

    f32x4 acc[4][4];
#pragma unroll
    for (int i = 0; i < 4; i++)
#pragma unroll
        for (int j = 0; j < 4; j++) { f32x4 zz = {0.f, 0.f, 0.f, 0.f}; acc[i][j] = zz; }

    for (int kk = 0; kk < DM_; kk += 32) {
        __syncthreads();
#pragma unroll
        for (int i = 0; i < 4; i++) {
            int idx = i * 256 + tid;
            int row = idx >> 3, k4 = (idx & 7) * 4;
            float4 v = *(const float4*)&X[(size_t)(m0 + row) * DM_ + kk + k4];
            uint2 o; o.x = pkbf(v.x, v.y); o.y = pkbf(v.z, v.w);
            *(uint2*)&As[row * 40 + k4] = o;
        }
#pragma unroll
        for (int i = 0; i < 2; i++) {
            int idx = i * 256 + tid;
            int row = idx >> 2, k8 = (idx & 3) * 8;
            uint4 v = *(const uint4*)&W[(size_t)(n0 + row) * DM_ + kk + k8];
            *(uint4*)&Bs[row * 40 + k8] = v;
        }
        __syncthreads();
        bf16x8 af[4], bf[4];
#pragma unroll
        for (int mt = 0; mt < 4; mt++) af[mt] = *(const bf16x8*)&As[(mb + mt * 16 + ln) * 40 + qd * 8];
#pragma unroll
        for (int nt = 0; nt < 4; nt++) bf[nt] = *(const bf16x8*)&Bs[(nb + nt * 16 + ln) * 40 + qd * 8];
#pragma unroll
        for (int mt = 0; mt < 4; mt++)
#pragma unroll
            for (int nt = 0; nt < 4; nt++)
                acc[mt][nt] = __builtin_amdgcn_mfma_f32_16x16x32_bf16(af[mt], bf[nt], acc[mt][nt], 0, 0, 0);
    }
    proj_epilogue(z, acc, bias, out, scale, m0, n0, mb, nb, ln, qd);
}

// ---------- flash attention (legacy single-pass, small-ws fallback) ----------
__global__ __launch_bounds__(256, 2) void flash_attn(const unsigned short* __restrict__ Qh,
                                                     const unsigned short* __restrict__ Kh,
                                                     const unsigned short* __restrict__ VhT,
                                                     unsigned short* __restrict__ Ao) {
    __shared__ unsigned short Ks[2][64 * 64];     // 16 KB
    __shared__ unsigned short Vs[2][64 * 64];     // 16 KB
    int i = blockIdx.x;
    int bh = (i & 7) + 8 * ((i >> 3) & 1);
    int qb = i >> 4;
    int tid = threadIdx.x;
    int w = tid >> 6, lane = tid & 63;
    int ln = lane & 31, hf = lane >> 5;
    int swz = ln & 7;
    int q0 = qb * 128 + w * 32;
    const unsigned short* Qp = Qh + (size_t)bh * S_LEN * DK_;
    const unsigned short* Kp = Kh + (size_t)bh * S_LEN * DK_;
    const unsigned short* Vp = VhT + (size_t)bh * DK_ * S_LEN;

    int sr = lane >> 3;
    int sc = (lane & 7) ^ sr;
    const unsigned short* ksrc = Kp + (size_t)(w * 16 + sr) * DK_ + sc * 8;
    const unsigned short* vsrc = Vp + (size_t)(w * 16 + sr) * S_LEN + sc * 8;

    bf16x8 qf[4];
#pragma unroll
    for (int s = 0; s < 4; s++)
        qf[s] = *(const bf16x8*)&Qp[(size_t)(q0 + ln) * DK_ + s * 16 + hf * 8];

    f32x16 oacc[2];
    { f32x16 z = {0.f}; oacc[0] = z; oacc[1] = z; }
    float lsum = 0.f;

    GLOAD_LDS16(ksrc, &Ks[0][w * 1024]);
    GLOAD_LDS16(ksrc + (size_t)8 * DK_, &Ks[0][w * 1024 + 512]);
    GLOAD_LDS16(vsrc, &Vs[0][w * 1024]);
    GLOAD_LDS16(vsrc + (size_t)8 * S_LEN, &Vs[0][w * 1024 + 512]);

    int p = 0;
    for (int ks = 0; ks < S_LEN; ks += 64, p ^= 1) {
        __syncthreads();
        if (ks + 64 < S_LEN) {
            const unsigned short* kn = ksrc + (size_t)(ks + 64) * DK_;
            const unsigned short* vn = vsrc + (ks + 64);
            GLOAD_LDS16(kn, &Ks[p ^ 1][w * 1024]);
            GLOAD_LDS16(kn + (size_t)8 * DK_, &Ks[p ^ 1][w * 1024 + 512]);
            GLOAD_LDS16(vn, &Vs[p ^ 1][w * 1024]);
            GLOAD_LDS16(vn + (size_t)8 * S_LEN, &Vs[p ^ 1][w * 1024 + 512]);
        }
        const unsigned short* KsT = &Ks[p][0];
        const unsigned short* VsT = &Vs[p][0];

#pragma unroll
        for (int kb = 0; kb < 2; kb++) {
            f32x16 st = {0.f};
#pragma unroll
            for (int s = 0; s < 4; s++) {
                bf16x8 kf = *(const bf16x8*)&KsT[(kb * 32 + ln) * 64 + ((2 * s + hf) ^ swz) * 8];
                st = __builtin_amdgcn_mfma_f32_32x32x16_bf16(kf, qf[s], st, 0, 0, 0);
            }
            float e[16];
#pragma unroll
            for (int r = 0; r < 16; r++) e[r] = EXP2F(st[r]);
            lsum += ((e[0] + e[1]) + (e[2] + e[3])) + ((e[4] + e[5]) + (e[6] + e[7]))
                  + ((e[8] + e[9]) + (e[10] + e[11])) + ((e[12] + e[13]) + (e[14] + e[15]));
            unsigned int g[8];
#pragma unroll
            for (int gi = 0; gi < 8; gi++) g[gi] = pkbf(e[2 * gi], e[2 * gi + 1]);
            pl32swap(g[0], g[2]); pl32swap(g[1], g[3]);
            pl32swap(g[4], g[6]); pl32swap(g[5], g[7]);
            bf16x8 b0, b1;
            { uint4v t = {g[0], g[1], g[2], g[3]}; __builtin_memcpy(&b0, &t, 16); }
            { uint4v t = {g[4], g[5], g[6], g[7]}; __builtin_memcpy(&b1, &t, 16); }
#pragma unroll
            for (int dt = 0; dt < 2; dt++) {
                int s0 = kb * 2;
                bf16x8 vf0 = *(const bf16x8*)&VsT[(dt * 32 + ln) * 64 + ((2 * s0 + hf) ^ swz) * 8];
                bf16x8 vf1 = *(const bf16x8*)&VsT[(dt * 32 + ln) * 64 + ((2 * s0 + 2 + hf) ^ swz) * 8];
                oacc[dt] = __builtin_amdgcn_mfma_f32_32x32x16_bf16(vf0, b0, oacc[dt], 0, 0, 0);
                oacc[dt] = __builtin_amdgcn_mfma_f32_32x32x16_bf16(vf1, b1, oacc[dt], 0, 0, 0);
            }
        }
    }

    float ltot = lsum + __shfl_xor(lsum, 32, 64);
    float inv = 1.0f / ltot;

    int bb = bh >> 3, hh = bh & 7;
    int token = bb * S_LEN + q0 + ln;
#pragma unroll
    for (int dt = 0; dt < 2; dt++)
#pragma unroll
        for (int gi = 0; gi < 8; gi++) {
            int d = dt * 32 + 2 * (gi & 1) + 8 * (gi >> 1) + 4 * hf;
            unsigned int o = pkbf(oacc[dt][2 * gi] * inv, oacc[dt][2 * gi + 1] * inv);
            *(unsigned int*)&Ao[(size_t)token * DM_ + hh * DK_ + d] = o;
        }
}

// ---------- fused split-K flash: 2 key-teams in ONE block, merge in LDS ----------
// r6 post-mortem: sp's 8.5us flash win == merge kernel cost (r0 vs r1 totals
// identical). Fix: both key-split halves live in one 512-thread block as two
// 4-wave teams, each with its own double-buffered K/V LDS (2 x 32KB = 64KB).
// Main loop is sp's VERBATIM per-wave work at the same occupancy (2 blk/CU x
// 8 waves = 16 waves/CU = 4/SIMD). Epilogue: team 1 dumps unnormalized O^T +
// lsum into the dead K/V LDS; team 0 adds, normalizes, writes bf16 Ao direct.
// Deletes: merge launch, 32MB Opart write, 32MB Opart read, 25MB flash write.
__global__ __launch_bounds__(512, 4) void flash_attn_f(const unsigned short* __restrict__ Qh,
                                                       const unsigned short* __restrict__ Kh,
                                                       const unsigned short* __restrict__ VhT,
                                                       unsigned short* __restrict__ Ao) {
    __shared__ __align__(16) unsigned char smem[65536];
    int i = blockIdx.x;
    int bh = i & 15;
    int qb = i >> 4;                               // 0..31
    int tid = threadIdx.x;
    int w = tid >> 6, lane = tid & 63;
    int team = w >> 2, wl = w & 3;
    int ln = lane & 31, hf = lane >> 5;
    int swz = ln & 7;
    int q0 = qb * 128 + wl * 32;
    int ks0 = team * (S_LEN / 2);
    int ks1 = ks0 + (S_LEN / 2);
    const unsigned short* Qp = Qh + (size_t)bh * S_LEN * DK_;
    const unsigned short* Kp = Kh + (size_t)bh * S_LEN * DK_;
    const unsigned short* Vp = VhT + (size_t)bh * DK_ * S_LEN;

    // per-team LDS: Ks[2][64*64] at team*32768, Vs[2][64*64] at +16384
    unsigned short* KsB = (unsigned short*)(smem + team * 32768);
    unsigned short* VsB = (unsigned short*)(smem + team * 32768 + 16384);

    int sr = lane >> 3;
    int sc = (lane & 7) ^ sr;
    const unsigned short* ksrc = Kp + (size_t)(wl * 16 + sr) * DK_ + sc * 8;
    const unsigned short* vsrc = Vp + (size_t)(wl * 16 + sr) * S_LEN + sc * 8;

    bf16x8 qf[4];
#pragma unroll
    for (int s = 0; s < 4; s++)
        qf[s] = *(const bf16x8*)&Qp[(size_t)(q0 + ln) * DK_ + s * 16 + hf * 8];

    f32x16 oacc[2];
    { f32x16 z = {0.f}; oacc[0] = z; oacc[1] = z; }
    float lsum = 0.f;

    GLOAD_LDS16(ksrc + (size_t)ks0 * DK_, &KsB[wl * 1024]);
    GLOAD_LDS16(ksrc + (size_t)(ks0 + 8) * DK_, &KsB[wl * 1024 + 512]);
    GLOAD_LDS16(vsrc + ks0, &VsB[wl * 1024]);
    GLOAD_LDS16(vsrc + ks0 + (size_t)8 * S_LEN, &VsB[wl * 1024 + 512]);

    int p = 0;
    for (int ks = ks0; ks < ks1; ks += 64, p ^= 1) {
        __syncthreads();   // drains DMA for buf p; all waves done reading buf p^1
        if (ks + 64 < ks1) {
            const unsigned short* kn = ksrc + (size_t)(ks + 64) * DK_;
            const unsigned short* vn = vsrc + (ks + 64);
            GLOAD_LDS16(kn, &KsB[(p ^ 1) * 4096 + wl * 1024]);
            GLOAD_LDS16(kn + (size_t)8 * DK_, &KsB[(p ^ 1) * 4096 + wl * 1024 + 512]);
            GLOAD_LDS16(vn, &VsB[(p ^ 1) * 4096 + wl * 1024]);
            GLOAD_LDS16(vn + (size_t)8 * S_LEN, &VsB[(p ^ 1) * 4096 + wl * 1024 + 512]);
        }
        const unsigned short* KsT = &KsB[p * 4096];
        const unsigned short* VsT = &VsB[p * 4096];

#pragma unroll
        for (int kb = 0; kb < 2; kb++) {
            f32x16 st = {0.f};
#pragma unroll
            for (int s = 0; s < 4; s++) {
                bf16x8 kf = *(const bf16x8*)&KsT[(kb * 32 + ln) * 64 + ((2 * s + hf) ^ swz) * 8];
                st = __builtin_amdgcn_mfma_f32_32x32x16_bf16(kf, qf[s], st, 0, 0, 0);
            }
            float e[16];
#pragma unroll
            for (int r = 0; r < 16; r++) e[r] = EXP2F(st[r]);
            lsum += ((e[0] + e[1]) + (e[2] + e[3])) + ((e[4] + e[5]) + (e[6] + e[7]))
                  + ((e[8] + e[9]) + (e[10] + e[11])) + ((e[12] + e[13]) + (e[14] + e[15]));
            unsigned int g[8];
#pragma unroll
            for (int gi = 0; gi < 8; gi++) g[gi] = pkbf(e[2 * gi], e[2 * gi + 1]);
            pl32swap(g[0], g[2]); pl32swap(g[1], g[3]);
            pl32swap(g[4], g[6]); pl32swap(g[5], g[7]);
            bf16x8 b0, b1;
            { uint4v t = {g[0], g[1], g[2], g[3]}; __builtin_memcpy(&b0, &t, 16); }
            { uint4v t = {g[4], g[5], g[6], g[7]}; __builtin_memcpy(&b1, &t, 16); }
#pragma unroll
            for (int dt = 0; dt < 2; dt++) {
                int s0 = kb * 2;
                bf16x8 vf0 = *(const bf16x8*)&VsT[(dt * 32 + ln) * 64 + ((2 * s0 + hf) ^ swz) * 8];
                bf16x8 vf1 = *(const bf16x8*)&VsT[(dt * 32 + ln) * 64 + ((2 * s0 + 2 + hf) ^ swz) * 8];
                oacc[dt] = __builtin_amdgcn_mfma_f32_32x32x16_bf16(vf0, b0, oacc[dt], 0, 0, 0);
                oacc[dt] = __builtin_amdgcn_mfma_f32_32x32x16_bf16(vf1, b1, oacc[dt], 0, 0, 0);
            }
        }
    }

    // per-team denominator (both lane-halves combined)
    float ltot = lsum + __shfl_xor(lsum, 32, 64);

    // ---- cross-team merge in LDS (K/V buffers are dead) ----
    __syncthreads();
    float* eps = (float*)smem;          // 8192 f32 = 32KB (team-0's region)
    float* epl = eps + 8192;            // 128 f32 for lsums (team-1's region)
    if (team == 1) {
#pragma unroll
        for (int dt = 0; dt < 2; dt++)
#pragma unroll
            for (int r = 0; r < 16; r++)
                eps[wl * 2048 + dt * 1024 + r * 64 + lane] = oacc[dt][r];
        if (hf == 0) epl[wl * 32 + ln] = ltot;
    }
    __syncthreads();
    if (team == 0) {
#pragma unroll
        for (int dt = 0; dt < 2; dt++)
#pragma unroll
            for (int r = 0; r < 16; r++)
                oacc[dt][r] += eps[wl * 2048 + dt * 1024 + r * 64 + lane];
        float inv = 1.0f / (ltot + epl[wl * 32 + ln]);

        int bb = bh >> 3, hh = bh & 7;
        int token = bb * S_LEN + q0 + ln;
#pragma unroll
        for (int dt = 0; dt < 2; dt++)
#pragma unroll
            for (int gi = 0; gi < 8; gi++) {
                int d = dt * 32 + 2 * (gi & 1) + 8 * (gi >> 1) + 4 * hf;
                unsigned int o = pkbf(oacc[dt][2 * gi] * inv, oacc[dt][2 * gi + 1] * inv);
                *(unsigned int*)&Ao[(size_t)token * DM_ + hh * DK_ + d] = o;
            }
    }
}

// ---------- output GEMM: out = Ao(bf16)@Wo + bo, fp32 out (LDS-DMA staged) ----------
__global__ __launch_bounds__(256, 3) void out_gemm(const unsigned short* __restrict__ A,
                                                   const unsigned short* __restrict__ Wt,
                                                   const float* __restrict__ bias, float* __restrict__ out) {
    __shared__ unsigned short As[128 * 32];
    __shared__ unsigned short Bs[128 * 32];
    int tid = threadIdx.x;
    int n0 = blockIdx.x * 128, m0 = blockIdx.y * 128;
    int w = tid >> 6, lane = tid & 63;
    int ln = lane & 15, qd = lane >> 4;
    int mb = (w >> 1) * 64, nb = (w & 1) * 64;

    int lr = lane >> 2;
    int cs = ((lane & 3) ^ (lr & 3)) * 8;
    int rdc = (qd ^ (ln & 3)) * 8;

    f32x4 acc[4][4];
#pragma unroll
    for (int i = 0; i < 4; i++)
#pragma unroll
        for (int j = 0; j < 4; j++) { f32x4 z = {0.f, 0.f, 0.f, 0.f}; acc[i][j] = z; }

    for (int kk = 0; kk < DM_; kk += 32) {
        __syncthreads();
#pragma unroll
        for (int j = 0; j < 2; j++) {
            int r0 = w * 32 + j * 16;
            GLOAD_LDS16(&A[(size_t)(m0 + r0 + lr) * DM_ + kk + cs], &As[r0 * 32]);
            GLOAD_LDS16(&Wt[(size_t)(n0 + r0 + lr) * DM_ + kk + cs], &Bs[r0 * 32]);
        }
        __syncthreads();
        bf16x8 af[4], bf[4];
#pragma unroll
        for (int mt = 0; mt < 4; mt++) af[mt] = *(const bf16x8*)&As[(mb + mt * 16 + ln) * 32 + rdc];
#pragma unroll
        for (int nt = 0; nt < 4; nt++) bf[nt] = *(const bf16x8*)&Bs[(nb + nt * 16 + ln) * 32 + rdc];
#pragma unroll
        for (int mt = 0; mt < 4; mt++)
#pragma unroll
            for (int nt = 0; nt < 4; nt++)
                acc[mt][nt] = __builtin_amdgcn_mfma_f32_16x16x32_bf16(af[mt], bf[nt], acc[mt][nt], 0, 0, 0);
    }

    float bv[4];
#pragma unroll
    for (int nt = 0; nt < 4; nt++) bv[nt] = bias[n0 + nb + nt * 16 + ln];
#pragma unroll
    for (int mt = 0; mt < 4; mt++) {
        int mrow0 = m0 + mb + mt * 16 + qd * 4;
#pragma unroll
        for (int nt = 0; nt < 4; nt++) {
            int ncol = n0 + nb + nt * 16 + ln;
#pragma unroll
            for (int r = 0; r < 4; r++)
                out[(size_t)(mrow0 + r) * DM_ + ncol] = acc[mt][nt][r] + bv[nt];
        }
    }
}

extern "C" void kernel_launch(void* const* d_in, const int* in_sizes, int n_in,
                              void* d_out, int out_size, void* d_ws, size_t ws_size,
                              hipStream_t stream) {
    const float* q  = (const float*)d_in[0];
    const float* k  = (const float*)d_in[1];
    const float* v  = (const float*)d_in[2];
    const float* Wq = (const float*)d_in[3];
    const float* bq = (const float*)d_in[4];
    const float* Wk = (const float*)d_in[5];
    const float* bk = (const float*)d_in[6];
    const float* Wv = (const float*)d_in[7];
    const float* bv = (const float*)d_in[8];
    const float* Wo = (const float*)d_in[9];
    const float* bo = (const float*)d_in[10];
    float* out = (float*)d_out;

    unsigned short* Wt  = (unsigned short*)d_ws;
    unsigned short* Qh  = Wt + (size_t)4 * DM_ * DM_;
    unsigned short* Kh  = Qh + (size_t)NTOK * DM_;
    unsigned short* VhT = Kh + (size_t)NTOK * DM_;
    unsigned short* tail = VhT + (size_t)NTOK * DM_;

    size_t need_bf = ((size_t)4 * DM_ * DM_ + (size_t)6 * NTOK * DM_) * 2;

    if (ws_size >= need_bf) {
        unsigned short* Xbf = tail;   // Ao aliases Xbf head (Xbf dead before flash writes Ao)
        unsigned short* Ao = tail;
        prep<<<dim3(4096, 4), 256, 0, stream>>>(q, k, v, Wq, Wk, Wv, Wo, Xbf, Wt);
        qkv_bf<<<dim3(4, 64, 3), 256, 0, stream>>>(Xbf, Wt, bq, bk, bv, Qh, Kh, VhT);
        flash_attn_f<<<dim3(512), 512, 0, stream>>>(Qh, Kh, VhT, Ao);
        out_gemm<<<dim3(4, 64), 256, 0, stream>>>(Ao, Wt + (size_t)3 * DM_ * DM_, bo, out);
    } else {
        unsigned short* Ao = tail;
        wtrans<<<dim3(8, 8, 4), 256, 0, stream>>>(Wq, Wk, Wv, Wo, Wt);
        qkv_proj<<<dim3(4, 64, 3), 256, 0, stream>>>(q, k, v, Wt, bq, bk, bv, Qh, Kh, VhT);
        flash_attn<<<dim3(512), 256, 0, stream>>>(Qh, Kh, VhT, Ao);
        out_gemm<<<dim3(4, 64), 256, 0, stream>>>(Ao, Wt + (size_t)3 * DM_ * DM_, bo, out);
    }
}